// Round 12
// baseline (1925.708 us; speedup 1.0000x reference)
//
#include <hip/hip_runtime.h>
#include <hip/hip_fp16.h>

typedef unsigned short u16;
typedef unsigned int u32;
typedef __attribute__((ext_vector_type(8))) unsigned short us8;
typedef __attribute__((ext_vector_type(8))) _Float16 f16x8;
typedef __attribute__((ext_vector_type(4))) float f32x4;

#define EPS 1e-5f

__device__ __forceinline__ float h2f(u16 h){ __half v; *(u16*)&v = h; return __half2float(v); }
__device__ __forceinline__ u16 f2h(float f){ __half v = __float2half(f); return *(u16*)&v; }
__device__ __forceinline__ u32 pkh(float a, float b){ return (u32)f2h(a) | ((u32)f2h(b) << 16); }

// ---------------- input projection: h = x @ W_in + b_in ----------------
__global__ __launch_bounds__(256) void k_in(const float* __restrict__ x,
    const float* __restrict__ Win, const float* __restrict__ bin,
    float* __restrict__ h, int N){
  __shared__ float Ws[18][64];
  __shared__ float xs[64][20];
  int tid = threadIdx.x;
  for (int i = tid; i < 18*64; i += 256) Ws[i>>6][i&63] = Win[i];
  int row0 = blockIdx.x * 64;
  for (int i = tid; i < 64*18; i += 256){
    int r = i/18, k = i - r*18;
    int row = row0 + r;
    xs[r][k] = (row < N) ? x[(size_t)row*18 + k] : 0.f;
  }
  __syncthreads();
  int rq = tid >> 4, dq = tid & 15;
  float4 b4 = *(const float4*)(bin + dq*4);
  float acc[4][4];
  #pragma unroll
  for (int j=0;j<4;j++){ acc[j][0]=b4.x; acc[j][1]=b4.y; acc[j][2]=b4.z; acc[j][3]=b4.w; }
  for (int k=0;k<18;k++){
    float4 wv = *(const float4*)&Ws[k][dq*4];
    #pragma unroll
    for (int j=0;j<4;j++){
      float v = xs[rq*4+j][k];
      acc[j][0]+=v*wv.x; acc[j][1]+=v*wv.y; acc[j][2]+=v*wv.z; acc[j][3]+=v*wv.w;
    }
  }
  #pragma unroll
  for (int j=0;j<4;j++){
    int row = row0 + rq*4 + j;
    if (row < N)
      *(float4*)(h + (size_t)row*64 + dq*4) = make_float4(acc[j][0],acc[j][1],acc[j][2],acc[j][3]);
  }
}

// ---------------- P = h@A, Q = h@B (fp16 out) ----------------
__global__ __launch_bounds__(256) void k_pq(const float* __restrict__ h,
    const float* __restrict__ A, const float* __restrict__ B,
    u16* __restrict__ P, u16* __restrict__ Q, int N){
  __shared__ float hs[64][68];
  __shared__ float As[64][64];
  __shared__ float Bs[64][64];
  int tid = threadIdx.x;
  for (int i = tid; i < 4096; i += 256){ As[i>>6][i&63] = A[i]; Bs[i>>6][i&63] = B[i]; }
  int row0 = blockIdx.x*64;
  for (int i = tid; i < 4096; i += 256){
    int r = i>>6, k = i&63; int row = row0+r;
    hs[r][k] = (row<N)? h[(size_t)row*64+k] : 0.f;
  }
  __syncthreads();
  int rq = tid>>4, dq = tid&15;
  float ap[4][4]={}, aq[4][4]={};
  for (int k=0;k<64;k+=4){
    float4 hv[4];
    #pragma unroll
    for (int j=0;j<4;j++) hv[j] = *(const float4*)&hs[rq*4+j][k];
    #pragma unroll
    for (int kk=0;kk<4;kk++){
      float4 av = *(const float4*)&As[k+kk][dq*4];
      float4 bv = *(const float4*)&Bs[k+kk][dq*4];
      #pragma unroll
      for (int j=0;j<4;j++){
        float v = ((const float*)&hv[j])[kk];
        ap[j][0]+=v*av.x; ap[j][1]+=v*av.y; ap[j][2]+=v*av.z; ap[j][3]+=v*av.w;
        aq[j][0]+=v*bv.x; aq[j][1]+=v*bv.y; aq[j][2]+=v*bv.z; aq[j][3]+=v*bv.w;
      }
    }
  }
  #pragma unroll
  for (int j=0;j<4;j++){
    int row = row0 + rq*4 + j;
    if (row<N){
      ushort4 pk, qk;
      pk.x=f2h(ap[j][0]); pk.y=f2h(ap[j][1]); pk.z=f2h(ap[j][2]); pk.w=f2h(ap[j][3]);
      qk.x=f2h(aq[j][0]); qk.y=f2h(aq[j][1]); qk.z=f2h(aq[j][2]); qk.w=f2h(aq[j][3]);
      *(ushort4*)(P+(size_t)row*64+dq*4) = pk;
      *(ushort4*)(Q+(size_t)row*64+dq*4) = qk;
    }
  }
}

// ================= CSR build (once, reused all 4 layers) =================
__global__ __launch_bounds__(256) void k_hist(const int* __restrict__ ei, int* __restrict__ cnt, int E){
  int e = blockIdx.x*256 + threadIdx.x;
  if (e < E) atomicAdd(&cnt[ei[E+e]], 1);
}

__global__ __launch_bounds__(256) void k_scan_a(const int* __restrict__ cnt, int* __restrict__ rp,
    int* __restrict__ bsum, int N){
  __shared__ int sm[256];
  int tid = threadIdx.x;
  int i0 = blockIdx.x*1024 + tid*4;
  int v0 = (i0+0<N)? cnt[i0+0]:0;
  int v1 = (i0+1<N)? cnt[i0+1]:0;
  int v2 = (i0+2<N)? cnt[i0+2]:0;
  int v3 = (i0+3<N)? cnt[i0+3]:0;
  int s = v0+v1+v2+v3;
  sm[tid] = s; __syncthreads();
  for (int ofs=1; ofs<256; ofs<<=1){
    int v = sm[tid];
    if (tid >= ofs) v += sm[tid-ofs];
    __syncthreads(); sm[tid] = v; __syncthreads();
  }
  int base = sm[tid] - s;
  int a0 = base+v0, a1 = a0+v1, a2 = a1+v2, a3 = a2+v3;
  if (i0+0<N) rp[i0+0]=a0;
  if (i0+1<N) rp[i0+1]=a1;
  if (i0+2<N) rp[i0+2]=a2;
  if (i0+3<N) rp[i0+3]=a3;
  if (tid==255) bsum[blockIdx.x] = sm[255];
}

__global__ void k_scan_b(int* __restrict__ bsum, int NB){
  if (threadIdx.x==0){
    int run = 0;
    for (int b=0;b<NB;b++){ int t = bsum[b]; bsum[b] = run; run += t; }
  }
}

__global__ __launch_bounds__(256) void k_scan_c(const int* __restrict__ cnt, int* __restrict__ rp,
    int* __restrict__ wr, const int* __restrict__ bsum, int N, int E){
  int tid = threadIdx.x;
  int i0 = blockIdx.x*1024 + tid*4;
  int off = bsum[blockIdx.x];
  #pragma unroll
  for (int j=0;j<4;j++){
    int i = i0+j;
    if (i<N){ int ex = off + rp[i] - cnt[i]; rp[i] = ex; wr[i] = ex; }
  }
  if (blockIdx.x==0 && tid==0) rp[N] = E;
}

// sorted packed array: seS[pos] = {src, edge_attr_bits}, pos in dst-sorted order
__global__ __launch_bounds__(256) void k_perm(const int* __restrict__ ei, const float* __restrict__ ea,
    int* __restrict__ wr, int2* __restrict__ seS, int E){
  int e = blockIdx.x*256 + threadIdx.x;
  if (e < E){
    int dn = ei[E+e];
    int pos = atomicAdd(&wr[dn], 1);
    seS[pos] = make_int2(ei[e], __float_as_int(ea[e]));
  }
}

// ------- node-centric gather (2 edge streams/wave, ushort2/lane): t + BN1 stats -------
__global__ __launch_bounds__(256) void k_t1s(const u16* __restrict__ P, const u16* __restrict__ Q,
    const int2* __restrict__ seS, const int* __restrict__ rp,
    const float* __restrict__ c1, const float* __restrict__ b1,
    u16* __restrict__ t, float* __restrict__ stats, int N){
  int tid = threadIdx.x;
  int lane = tid & 63, w = tid >> 6;
  int sub = lane >> 5;
  int dl = (lane & 31) * 2;
  float cv0 = c1[dl], cv1 = c1[dl+1];
  float bv0 = b1[dl], bv1 = b1[dl+1];
  float s0 = 0.f, s1 = 0.f, qs0 = 0.f, qs1 = 0.f;
  for (int n = blockIdx.x*4 + w; n < N; n += gridDim.x*4){
    int a = rp[n], b = rp[n+1];
    u32 pp = *(const u32*)(P + (size_t)n*64 + dl);
    float p0 = h2f((u16)(pp & 0xffffu)) + bv0;
    float p1 = h2f((u16)(pp >> 16)) + bv1;
    int p = a + sub;
    for (; p + 2 < b; p += 4){
      int2 seA = seS[p];
      int2 seB = seS[p+2];
      u32 qA = *(const u32*)(Q + (size_t)seA.x*64 + dl);
      u32 qB = *(const u32*)(Q + (size_t)seB.x*64 + dl);
      float eaA = __int_as_float(seA.y), eaB = __int_as_float(seB.y);
      float tA0 = p0 + h2f((u16)(qA & 0xffffu)) + eaA*cv0;
      float tA1 = p1 + h2f((u16)(qA >> 16)) + eaA*cv1;
      float tB0 = p0 + h2f((u16)(qB & 0xffffu)) + eaB*cv0;
      float tB1 = p1 + h2f((u16)(qB >> 16)) + eaB*cv1;
      *(u32*)(t + (size_t)p*64 + dl) = (u32)f2h(tA0) | ((u32)f2h(tA1) << 16);
      *(u32*)(t + (size_t)(p+2)*64 + dl) = (u32)f2h(tB0) | ((u32)f2h(tB1) << 16);
      s0 += tA0 + tB0; s1 += tA1 + tB1;
      qs0 += tA0*tA0 + tB0*tB0; qs1 += tA1*tA1 + tB1*tB1;
    }
    for (; p < b; p += 2){
      int2 se = seS[p];
      u32 qq = *(const u32*)(Q + (size_t)se.x*64 + dl);
      float ea = __int_as_float(se.y);
      float t0 = p0 + h2f((u16)(qq & 0xffffu)) + ea*cv0;
      float t1 = p1 + h2f((u16)(qq >> 16)) + ea*cv1;
      *(u32*)(t + (size_t)p*64 + dl) = (u32)f2h(t0) | ((u32)f2h(t1) << 16);
      s0 += t0; s1 += t1; qs0 += t0*t0; qs1 += t1*t1;
    }
  }
  __shared__ float sS[8][64], qS[8][64];
  int idx = w*2 + sub;
  sS[idx][dl] = s0; sS[idx][dl+1] = s1;
  qS[idx][dl] = qs0; qS[idx][dl+1] = qs1;
  __syncthreads();
  if (tid < 64){
    float ts = 0.f, tq = 0.f;
    #pragma unroll
    for (int r=0;r<8;r++){ ts += sS[r][tid]; tq += qS[r][tid]; }
    atomicAdd(&stats[tid], ts);
    atomicAdd(&stats[64+tid], tq);
  }
}

// ---- msg layer2 (MFMA, pipelined 128-edge tiles, swapped-operand epilogue) ----
__global__ __launch_bounds__(256) void k_m2s(u16* __restrict__ t,
    const float* __restrict__ g1, const float* __restrict__ be1, const float* __restrict__ stats1,
    const float* __restrict__ W2, const float* __restrict__ b2,
    float* __restrict__ stats2, int E, float invE){
  __shared__ _Float16 yL[128][72];
  __shared__ _Float16 wL[64][72];
  __shared__ float scS[64], shS[64], b2S[64];
  int tid = threadIdx.x;
  if (tid < 64){
    float m = stats1[tid]*invE;
    float v = stats1[64+tid]*invE - m*m;
    float sc = g1[tid]*rsqrtf(v + EPS);
    scS[tid] = sc; shS[tid] = be1[tid] - m*sc;
    b2S[tid] = b2[tid];
  }
  for (int i = tid; i < 4096; i += 256){
    int k = i >> 6, n = i & 63;
    wL[n][k] = (_Float16)W2[i];
  }
  __syncthreads();
  int lane = tid & 63, wv = tid >> 6;
  int arow = lane & 15;
  int kgrp = lane >> 4;
  int srow = tid >> 1, sc0 = (tid & 1)*32;
  float bb[4][4];
  #pragma unroll
  for (int c=0;c<4;c++){
    #pragma unroll
    for (int r=0;r<4;r++) bb[c][r] = b2S[16*c + 4*kgrp + r];
  }
  float ssum[4][4] = {}, ssq[4][4] = {};
  int ntiles = (E + 127) >> 7;
  f16x8 ra, rb, rc, rd;
  {
    f16x8 z;
    #pragma unroll
    for (int j=0;j<8;j++) z[j] = (_Float16)0.f;
    ra = rb = rc = rd = z;
    int tile = blockIdx.x;
    int p = tile*128 + srow;
    if (tile < ntiles && p < E){
      const u16* src = t + (size_t)p*64 + sc0;
      ra = *(const f16x8*)(src);
      rb = *(const f16x8*)(src + 8);
      rc = *(const f16x8*)(src + 16);
      rd = *(const f16x8*)(src + 24);
    }
  }
  for (int tile = blockIdx.x; tile < ntiles; tile += gridDim.x){
    int e0 = tile << 7;
    {
      f16x8 v;
      #pragma unroll
      for (int j=0;j<8;j++){ int dd = sc0 + j;      v[j] = (_Float16)fmaxf((float)ra[j]*scS[dd] + shS[dd], 0.f); }
      *(f16x8*)&yL[srow][sc0]      = v;
      #pragma unroll
      for (int j=0;j<8;j++){ int dd = sc0 + 8 + j;  v[j] = (_Float16)fmaxf((float)rb[j]*scS[dd] + shS[dd], 0.f); }
      *(f16x8*)&yL[srow][sc0 + 8]  = v;
      #pragma unroll
      for (int j=0;j<8;j++){ int dd = sc0 + 16 + j; v[j] = (_Float16)fmaxf((float)rc[j]*scS[dd] + shS[dd], 0.f); }
      *(f16x8*)&yL[srow][sc0 + 16] = v;
      #pragma unroll
      for (int j=0;j<8;j++){ int dd = sc0 + 24 + j; v[j] = (_Float16)fmaxf((float)rd[j]*scS[dd] + shS[dd], 0.f); }
      *(f16x8*)&yL[srow][sc0 + 24] = v;
    }
    {
      int nt = tile + gridDim.x;
      if (nt < ntiles){
        int p = nt*128 + srow;
        if (p < E){
          const u16* src = t + (size_t)p*64 + sc0;
          ra = *(const f16x8*)(src);
          rb = *(const f16x8*)(src + 8);
          rc = *(const f16x8*)(src + 16);
          rd = *(const f16x8*)(src + 24);
        } else {
          f16x8 z;
          #pragma unroll
          for (int j=0;j<8;j++) z[j] = (_Float16)0.f;
          ra = rb = rc = rd = z;
        }
      }
    }
    __syncthreads();
    #pragma unroll
    for (int mf=0; mf<2; mf++){
      int row = 32*wv + 16*mf + arow;
      f16x8 y0 = *(const f16x8*)&yL[row][8*kgrp];
      f16x8 y1 = *(const f16x8*)&yL[row][32 + 8*kgrp];
      int e = e0 + 32*wv + 16*mf + arow;
      #pragma unroll
      for (int c=0;c<4;c++){
        f16x8 w0 = *(const f16x8*)&wL[16*c + arow][8*kgrp];
        f16x8 w1 = *(const f16x8*)&wL[16*c + arow][32 + 8*kgrp];
        f32x4 d = {0.f,0.f,0.f,0.f};
        d = __builtin_amdgcn_mfma_f32_16x16x32_f16(w0, y0, d, 0, 0, 0);
        d = __builtin_amdgcn_mfma_f32_16x16x32_f16(w1, y1, d, 0, 0, 0);
        if (e < E){
          float v0 = d[0] + bb[c][0];
          float v1 = d[1] + bb[c][1];
          float v2 = d[2] + bb[c][2];
          float v3 = d[3] + bb[c][3];
          ushort4 st;
          st.x = f2h(v0); st.y = f2h(v1); st.z = f2h(v2); st.w = f2h(v3);
          *(ushort4*)(t + (size_t)e*64 + 16*c + 4*kgrp) = st;
          ssum[c][0]+=v0; ssum[c][1]+=v1; ssum[c][2]+=v2; ssum[c][3]+=v3;
          ssq[c][0]+=v0*v0; ssq[c][1]+=v1*v1; ssq[c][2]+=v2*v2; ssq[c][3]+=v3*v3;
        }
      }
    }
    __syncthreads();
  }
  float* red = (float*)yL;
  int slot = wv*16 + arow;
  #pragma unroll
  for (int c=0;c<4;c++){
    #pragma unroll
    for (int r=0;r<4;r++)
      red[(16*c + 4*kgrp + r)*64 + slot] = ssum[c][r];
  }
  __syncthreads();
  if (tid < 64){
    float s = 0.f;
    for (int g=0; g<64; g++) s += red[tid*64 + g];
    atomicAdd(&stats2[tid], s);
  }
  __syncthreads();
  #pragma unroll
  for (int c=0;c<4;c++){
    #pragma unroll
    for (int r=0;r<4;r++)
      red[(16*c + 4*kgrp + r)*64 + slot] = ssq[c][r];
  }
  __syncthreads();
  if (tid < 64){
    float s = 0.f;
    for (int g=0; g<64; g++) s += red[tid*64 + g];
    atomicAdd(&stats2[64+tid], s);
  }
}

// ---- FUSED: agg (segment-sum of relu(bn2(t2))) + upd layer1 MFMA (K=128) + stats3 ----
__global__ __launch_bounds__(256) void k_aggup1(const float* __restrict__ h,
    const u16* __restrict__ t2, const int* __restrict__ rp,
    const float* __restrict__ g2, const float* __restrict__ be2, const float* __restrict__ stats2,
    const float* __restrict__ U1, const float* __restrict__ b1u,
    float* __restrict__ tn, float* __restrict__ stats3, int N, float invE){
  __shared__ _Float16 yL[64][136];
  __shared__ _Float16 wL[64][136];
  __shared__ float scS[64], shS[64], bS[64];
  int tid = threadIdx.x;
  if (tid < 64){
    float m = stats2[tid]*invE;
    float v = stats2[64+tid]*invE - m*m;
    float sc = g2[tid]*rsqrtf(v+EPS);
    scS[tid] = sc; shS[tid] = be2[tid] - m*sc;
    bS[tid] = b1u[tid];
  }
  for (int i = tid; i < 8192; i += 256){
    int k = i >> 6, n = i & 63;
    wL[n][k] = (_Float16)U1[i];
  }
  int row0 = blockIdx.x * 64;
  int srow = tid >> 2, sc0 = (tid & 3) * 16;
  {
    int row = row0 + srow;
    if (row < N){
      #pragma unroll
      for (int c=0;c<4;c++){
        float4 v = *(const float4*)(h + (size_t)row*64 + sc0 + 4*c);
        *(u32*)&yL[srow][sc0+4*c]   = pkh(v.x, v.y);
        *(u32*)&yL[srow][sc0+4*c+2] = pkh(v.z, v.w);
      }
    } else {
      #pragma unroll
      for (int c=0;c<4;c++){
        *(u32*)&yL[srow][sc0+4*c] = 0u; *(u32*)&yL[srow][sc0+4*c+2] = 0u;
      }
    }
  }
  __syncthreads();
  // agg phase: wave w computes segment sums for its 16 nodes; write fp16 into yL cols 64..127
  {
    int lane = tid & 63, w = tid >> 6;
    int sub = lane >> 5;
    int dl = (lane & 31) * 2;
    float sc0f = scS[dl], sc1f = scS[dl+1], sh0 = shS[dl], sh1 = shS[dl+1];
    for (int i=0;i<16;i++){
      int n = row0 + w*16 + i;
      float a0 = 0.f, a1 = 0.f;
      if (n < N){
        int a = rp[n], b = rp[n+1];
        int p = a + sub;
        for (; p + 2 < b; p += 4){
          u32 vA = *(const u32*)(t2 + (size_t)p*64 + dl);
          u32 vB = *(const u32*)(t2 + (size_t)(p+2)*64 + dl);
          a0 += fmaxf(h2f((u16)(vA & 0xffffu))*sc0f + sh0, 0.f)
              + fmaxf(h2f((u16)(vB & 0xffffu))*sc0f + sh0, 0.f);
          a1 += fmaxf(h2f((u16)(vA >> 16))*sc1f + sh1, 0.f)
              + fmaxf(h2f((u16)(vB >> 16))*sc1f + sh1, 0.f);
        }
        for (; p < b; p += 2){
          u32 vA = *(const u32*)(t2 + (size_t)p*64 + dl);
          a0 += fmaxf(h2f((u16)(vA & 0xffffu))*sc0f + sh0, 0.f);
          a1 += fmaxf(h2f((u16)(vA >> 16))*sc1f + sh1, 0.f);
        }
      }
      a0 += __shfl_xor(a0, 32);
      a1 += __shfl_xor(a1, 32);
      if (sub == 0)
        *(u32*)&yL[w*16 + i][64 + dl] = pkh(a0, a1);
    }
  }
  __syncthreads();
  int lane = tid & 63, wv = tid >> 6;
  int arow = lane & 15, kgrp = lane >> 4;
  f16x8 a[4];
  #pragma unroll
  for (int kk=0;kk<4;kk++) a[kk] = *(const f16x8*)&yL[16*wv + arow][32*kk + 8*kgrp];
  float ssum[4]={}, ssq[4]={};
  #pragma unroll
  for (int c=0;c<4;c++){
    f32x4 d = {0.f,0.f,0.f,0.f};
    #pragma unroll
    for (int kk=0;kk<4;kk++){
      f16x8 b = *(const f16x8*)&wL[16*c + arow][32*kk + 8*kgrp];
      d = __builtin_amdgcn_mfma_f32_16x16x32_f16(a[kk], b, d, 0, 0, 0);
    }
    int col = 16*c + arow;
    float bb = bS[col];
    #pragma unroll
    for (int r=0;r<4;r++){
      int row = row0 + 16*wv + 4*kgrp + r;
      if (row < N){
        float v = d[r] + bb;
        tn[(size_t)row*64 + col] = v;
        ssum[c]+=v; ssq[c]+=v*v;
      }
    }
  }
  __syncthreads();
  float* red = (float*)yL;
  #pragma unroll
  for (int c=0;c<4;c++) red[c*256 + tid] = ssum[c];
  __syncthreads();
  if (tid < 64){
    int cc = tid >> 4;
    float s = 0.f;
    for (int g=0; g<16; g++) s += red[cc*256 + g*16 + (tid & 15)];
    atomicAdd(&stats3[tid], s);
  }
  __syncthreads();
  #pragma unroll
  for (int c=0;c<4;c++) red[c*256 + tid] = ssq[c];
  __syncthreads();
  if (tid < 64){
    int cc = tid >> 4;
    float s = 0.f;
    for (int g=0; g<16; g++) s += red[cc*256 + g*16 + (tid & 15)];
    atomicAdd(&stats3[64+tid], s);
  }
}

// ======== Plan-B fallback (small ws): stats pass + recompute scatter ========
__global__ __launch_bounds__(256) void k_s1(const u16* __restrict__ P, const u16* __restrict__ Q,
    const float* __restrict__ ea, const int* __restrict__ ei,
    const float* __restrict__ c1, const float* __restrict__ b1,
    float* __restrict__ stats, int E){
  int tid = threadIdx.x;
  int d = tid & 63, w = tid >> 6;
  float cv = c1[d], bv = b1[d];
  float s = 0.f, sq = 0.f;
  for (int e = blockIdx.x*4 + w; e < E; e += gridDim.x*4){
    int dn = ei[E+e], sn = ei[e];
    float t = h2f(P[(size_t)dn*64+d]) + h2f(Q[(size_t)sn*64+d]) + ea[e]*cv + bv;
    s += t; sq += t*t;
  }
  __shared__ float sS[4][64], qS[4][64];
  sS[w][d] = s; qS[w][d] = sq;
  __syncthreads();
  if (tid < 64){
    float ts = sS[0][tid]+sS[1][tid]+sS[2][tid]+sS[3][tid];
    float tq = qS[0][tid]+qS[1][tid]+qS[2][tid]+qS[3][tid];
    atomicAdd(&stats[tid], ts);
    atomicAdd(&stats[64+tid], tq);
  }
}

__global__ __launch_bounds__(256) void k_m2b(const u16* __restrict__ P, const u16* __restrict__ Q,
    const float* __restrict__ ea, const int* __restrict__ ei,
    const float* __restrict__ c1, const float* __restrict__ b1,
    const float* __restrict__ g1, const float* __restrict__ be1,
    const float* __restrict__ stats1,
    const float* __restrict__ W2, const float* __restrict__ b2,
    float* __restrict__ stats2, int E, float invE){
  __shared__ float ys[64][68];
  __shared__ float Ws[64][64];
  __shared__ float scS[64], c1S[64], bS[64], b2S[64];
  int tid = threadIdx.x;
  if (tid < 64){
    float m = stats1[tid]*invE;
    float v = stats1[64+tid]*invE - m*m;
    float sc = g1[tid]*rsqrtf(v + EPS);
    float sh = be1[tid] - m*sc;
    scS[tid] = sc;
    c1S[tid] = c1[tid]*sc;
    bS[tid]  = b1[tid]*sc + sh;
    b2S[tid] = b2[tid];
  }
  for (int i=tid;i<4096;i+=256) Ws[i>>6][i&63] = W2[i];
  __syncthreads();
  int rq = tid>>4, dq = tid&15;
  float ssum[4]={}, ssq[4]={};
  int ntiles = (E+63)>>6;
  for (int tile = blockIdx.x; tile < ntiles; tile += gridDim.x){
    int e0 = tile<<6;
    for (int i = tid; i < 4096; i += 256){
      int el = i>>6, dd = i&63;
      int e = e0 + el;
      float y = 0.f;
      if (e < E){
        int dn = ei[E+e], sn = ei[e];
        float t = (h2f(P[(size_t)dn*64+dd]) + h2f(Q[(size_t)sn*64+dd]))*scS[dd] + ea[e]*c1S[dd] + bS[dd];
        y = fmaxf(t, 0.f);
      }
      ys[el][dd] = y;
    }
    __syncthreads();
    float acc[4][4];
    float4 b4 = *(const float4*)&b2S[dq*4];
    #pragma unroll
    for (int j=0;j<4;j++){ acc[j][0]=b4.x; acc[j][1]=b4.y; acc[j][2]=b4.z; acc[j][3]=b4.w; }
    for (int k=0;k<64;k+=4){
      float4 hv[4];
      #pragma unroll
      for (int j=0;j<4;j++) hv[j] = *(const float4*)&ys[rq*4+j][k];
      #pragma unroll
      for (int kk=0;kk<4;kk++){
        float4 wv = *(const float4*)&Ws[k+kk][dq*4];
        #pragma unroll
        for (int j=0;j<4;j++){
          float v = ((const float*)&hv[j])[kk];
          acc[j][0]+=v*wv.x; acc[j][1]+=v*wv.y; acc[j][2]+=v*wv.z; acc[j][3]+=v*wv.w;
        }
      }
    }
    #pragma unroll
    for (int j=0;j<4;j++){
      int e = e0 + rq*4 + j;
      if (e < E){
        #pragma unroll
        for (int c=0;c<4;c++){ float v=acc[j][c]; ssum[c]+=v; ssq[c]+=v*v; }
      }
    }
    __syncthreads();
  }
  float* red = &ys[0][0];
  #pragma unroll
  for (int c=0;c<4;c++) red[rq*64 + dq*4 + c] = ssum[c];
  __syncthreads();
  if (tid < 64){
    float t=0.f;
    for (int r=0;r<16;r++) t += red[r*64+tid];
    atomicAdd(&stats2[tid], t);
  }
  __syncthreads();
  #pragma unroll
  for (int c=0;c<4;c++) red[rq*64 + dq*4 + c] = ssq[c];
  __syncthreads();
  if (tid < 64){
    float t=0.f;
    for (int r=0;r<16;r++) t += red[r*64+tid];
    atomicAdd(&stats2[64+tid], t);
  }
}

__global__ __launch_bounds__(256) void k_sc_rec(const u16* __restrict__ P, const u16* __restrict__ Q,
    const float* __restrict__ ea, const int* __restrict__ ei,
    const float* __restrict__ c1, const float* __restrict__ b1,
    const float* __restrict__ g1, const float* __restrict__ be1, const float* __restrict__ stats1,
    const float* __restrict__ W2, const float* __restrict__ b2,
    const float* __restrict__ g2, const float* __restrict__ be2, const float* __restrict__ stats2,
    float* __restrict__ agg, int E, float invE){
  __shared__ float ys[64][68];
  __shared__ float Ws[64][64];
  __shared__ float scS[64], c1S[64], bS[64];
  __shared__ float s2S[64], h2S[64], b2S[64];
  int tid = threadIdx.x;
  if (tid < 64){
    float m = stats1[tid]*invE;
    float v = stats1[64+tid]*invE - m*m;
    float sc = g1[tid]*rsqrtf(v + EPS);
    scS[tid] = sc;
    c1S[tid] = c1[tid]*sc;
    bS[tid]  = b1[tid]*sc + be1[tid] - m*sc;
    float m2 = stats2[tid]*invE;
    float v2 = stats2[64+tid]*invE - m2*m2;
    float sc2 = g2[tid]*rsqrtf(v2+EPS);
    s2S[tid] = sc2; h2S[tid] = be2[tid] - m2*sc2;
    b2S[tid] = b2[tid];
  }
  for (int i=tid;i<4096;i+=256) Ws[i>>6][i&63] = W2[i];
  __syncthreads();
  int rq = tid>>4, dq = tid&15;
  int ntiles = (E+63)>>6;
  for (int tile = blockIdx.x; tile < ntiles; tile += gridDim.x){
    int e0 = tile<<6;
    for (int i = tid; i < 4096; i += 256){
      int el = i>>6, dd = i&63;
      int e = e0 + el;
      float y = 0.f;
      if (e < E){
        int dn = ei[E+e], sn = ei[e];
        float t = (h2f(P[(size_t)dn*64+dd]) + h2f(Q[(size_t)sn*64+dd]))*scS[dd] + ea[e]*c1S[dd] + bS[dd];
        y = fmaxf(t, 0.f);
      }
      ys[el][dd] = y;
    }
    __syncthreads();
    float acc[4][4];
    float4 b4 = *(const float4*)&b2S[dq*4];
    #pragma unroll
    for (int j=0;j<4;j++){ acc[j][0]=b4.x; acc[j][1]=b4.y; acc[j][2]=b4.z; acc[j][3]=b4.w; }
    for (int k=0;k<64;k+=4){
      float4 hv[4];
      #pragma unroll
      for (int j=0;j<4;j++) hv[j] = *(const float4*)&ys[rq*4+j][k];
      #pragma unroll
      for (int kk=0;kk<4;kk++){
        float4 wv = *(const float4*)&Ws[k+kk][dq*4];
        #pragma unroll
        for (int j=0;j<4;j++){
          float v = ((const float*)&hv[j])[kk];
          acc[j][0]+=v*wv.x; acc[j][1]+=v*wv.y; acc[j][2]+=v*wv.z; acc[j][3]+=v*wv.w;
        }
      }
    }
    float4 sc4 = *(const float4*)&s2S[dq*4];
    float4 sh4 = *(const float4*)&h2S[dq*4];
    #pragma unroll
    for (int j=0;j<4;j++){
      int e = e0 + rq*4 + j;
      if (e < E){
        int dn = ei[E+e];
        float y0 = fmaxf(acc[j][0]*sc4.x + sh4.x, 0.f);
        float y1 = fmaxf(acc[j][1]*sc4.y + sh4.y, 0.f);
        float y2 = fmaxf(acc[j][2]*sc4.z + sh4.z, 0.f);
        float y3 = fmaxf(acc[j][3]*sc4.w + sh4.w, 0.f);
        atomicAdd(&agg[(size_t)dn*64 + dq*4    ], y0);
        atomicAdd(&agg[(size_t)dn*64 + dq*4 + 1], y1);
        atomicAdd(&agg[(size_t)dn*64 + dq*4 + 2], y2);
        atomicAdd(&agg[(size_t)dn*64 + dq*4 + 3], y3);
      }
    }
    __syncthreads();
  }
}

// ---- plan-B upd layer1 (MFMA, K=128): tn = [h,agg] @ U1 + b + stats3 ----
__global__ __launch_bounds__(256) void k_up1(const float* __restrict__ h, const float* __restrict__ agg,
    const float* __restrict__ U1, const float* __restrict__ b1u,
    float* __restrict__ tn, float* __restrict__ stats3, int N){
  __shared__ _Float16 yL[64][136];
  __shared__ _Float16 wL[64][136];
  __shared__ float bS[64];
  int tid = threadIdx.x;
  if (tid < 64) bS[tid] = b1u[tid];
  for (int i = tid; i < 8192; i += 256){
    int k = i >> 6, n = i & 63;
    wL[n][k] = (_Float16)U1[i];
  }
  int row0 = blockIdx.x * 64;
  int srow = tid >> 2, sc0 = (tid & 3) * 16;
  {
    int row = row0 + srow;
    if (row < N){
      #pragma unroll
      for (int c=0;c<4;c++){
        float4 v = *(const float4*)(h + (size_t)row*64 + sc0 + 4*c);
        *(u32*)&yL[srow][sc0+4*c]   = pkh(v.x, v.y);
        *(u32*)&yL[srow][sc0+4*c+2] = pkh(v.z, v.w);
      }
      #pragma unroll
      for (int c=0;c<4;c++){
        float4 v = *(const float4*)(agg + (size_t)row*64 + sc0 + 4*c);
        *(u32*)&yL[srow][64+sc0+4*c]   = pkh(v.x, v.y);
        *(u32*)&yL[srow][64+sc0+4*c+2] = pkh(v.z, v.w);
      }
    } else {
      #pragma unroll
      for (int c=0;c<4;c++){
        *(u32*)&yL[srow][sc0+4*c] = 0u; *(u32*)&yL[srow][sc0+4*c+2] = 0u;
        *(u32*)&yL[srow][64+sc0+4*c] = 0u; *(u32*)&yL[srow][64+sc0+4*c+2] = 0u;
      }
    }
  }
  __syncthreads();
  int lane = tid & 63, wv = tid >> 6;
  int arow = lane & 15, kgrp = lane >> 4;
  f16x8 a[4];
  #pragma unroll
  for (int kk=0;kk<4;kk++) a[kk] = *(const f16x8*)&yL[16*wv + arow][32*kk + 8*kgrp];
  float ssum[4]={}, ssq[4]={};
  #pragma unroll
  for (int c=0;c<4;c++){
    f32x4 d = {0.f,0.f,0.f,0.f};
    #pragma unroll
    for (int kk=0;kk<4;kk++){
      f16x8 b = *(const f16x8*)&wL[16*c + arow][32*kk + 8*kgrp];
      d = __builtin_amdgcn_mfma_f32_16x16x32_f16(a[kk], b, d, 0, 0, 0);
    }
    int col = 16*c + arow;
    float bb = bS[col];
    #pragma unroll
    for (int r=0;r<4;r++){
      int row = row0 + 16*wv + 4*kgrp + r;
      if (row < N){
        float v = d[r] + bb;
        tn[(size_t)row*64 + col] = v;
        ssum[c]+=v; ssq[c]+=v*v;
      }
    }
  }
  __syncthreads();
  float* red = (float*)yL;
  #pragma unroll
  for (int c=0;c<4;c++) red[c*256 + tid] = ssum[c];
  __syncthreads();
  if (tid < 64){
    int cc = tid >> 4;
    float s = 0.f;
    for (int g=0; g<16; g++) s += red[cc*256 + g*16 + (tid & 15)];
    atomicAdd(&stats3[tid], s);
  }
  __syncthreads();
  #pragma unroll
  for (int c=0;c<4;c++) red[c*256 + tid] = ssq[c];
  __syncthreads();
  if (tid < 64){
    int cc = tid >> 4;
    float s = 0.f;
    for (int g=0; g<16; g++) s += red[cc*256 + g*16 + (tid & 15)];
    atomicAdd(&stats3[64+tid], s);
  }
}

// ---- upd layer2 (MFMA, K=64): tn = relu(bn3(tn)) @ U2 + b2 (in place) + stats4 ----
__global__ __launch_bounds__(256) void k_up2(float* __restrict__ tn,
    const float* __restrict__ g3, const float* __restrict__ be3, const float* __restrict__ stats3,
    const float* __restrict__ U2, const float* __restrict__ b2u,
    float* __restrict__ stats4, int N, float invN){
  __shared__ _Float16 yL[64][72];
  __shared__ _Float16 wL[64][72];
  __shared__ float scS[64], shS[64], bS[64];
  int tid = threadIdx.x;
  if (tid < 64){
    float m = stats3[tid]*invN;
    float v = stats3[64+tid]*invN - m*m;
    float sc = g3[tid]*rsqrtf(v+EPS);
    scS[tid] = sc; shS[tid] = be3[tid] - m*sc; bS[tid] = b2u[tid];
  }
  for (int i = tid; i < 4096; i += 256){
    int k = i >> 6, n = i & 63;
    wL[n][k] = (_Float16)U2[i];
  }
  __syncthreads();
  int row0 = blockIdx.x * 64;
  int srow = tid >> 2, sc0 = (tid & 3) * 16;
  {
    int row = row0 + srow;
    if (row < N){
      #pragma unroll
      for (int c=0;c<4;c++){
        float4 v = *(const float4*)(tn + (size_t)row*64 + sc0 + 4*c);
        int d0 = sc0 + 4*c;
        float y0 = fmaxf(v.x*scS[d0  ] + shS[d0  ], 0.f);
        float y1 = fmaxf(v.y*scS[d0+1] + shS[d0+1], 0.f);
        float y2 = fmaxf(v.z*scS[d0+2] + shS[d0+2], 0.f);
        float y3 = fmaxf(v.w*scS[d0+3] + shS[d0+3], 0.f);
        *(u32*)&yL[srow][d0]   = pkh(y0, y1);
        *(u32*)&yL[srow][d0+2] = pkh(y2, y3);
      }
    } else {
      #pragma unroll
      for (int c=0;c<4;c++){
        *(u32*)&yL[srow][sc0+4*c] = 0u; *(u32*)&yL[srow][sc0+4*c+2] = 0u;
      }
    }
  }
  __syncthreads();
  int lane = tid & 63, wv = tid >> 6;
  int arow = lane & 15, kgrp = lane >> 4;
  f16x8 a0 = *(const f16x8*)&yL[16*wv + arow][8*kgrp];
  f16x8 a1 = *(const f16x8*)&yL[16*wv + arow][32 + 8*kgrp];
  float ssum[4]={}, ssq[4]={};
  #pragma unroll
  for (int c=0;c<4;c++){
    f16x8 b0 = *(const f16x8*)&wL[16*c + arow][8*kgrp];
    f16x8 b1 = *(const f16x8*)&wL[16*c + arow][32 + 8*kgrp];
    f32x4 d = {0.f,0.f,0.f,0.f};
    d = __builtin_amdgcn_mfma_f32_16x16x32_f16(a0, b0, d, 0, 0, 0);
    d = __builtin_amdgcn_mfma_f32_16x16x32_f16(a1, b1, d, 0, 0, 0);
    int col = 16*c + arow;
    float bb = bS[col];
    #pragma unroll
    for (int r=0;r<4;r++){
      int row = row0 + 16*wv + 4*kgrp + r;
      if (row < N){
        float v = d[r] + bb;
        tn[(size_t)row*64 + col] = v;
        ssum[c]+=v; ssq[c]+=v*v;
      }
    }
  }
  __syncthreads();
  float* red = (float*)yL;
  #pragma unroll
  for (int c=0;c<4;c++) red[c*256 + tid] = ssum[c];
  __syncthreads();
  if (tid < 64){
    int cc = tid >> 4;
    float s = 0.f;
    for (int g=0; g<16; g++) s += red[cc*256 + g*16 + (tid & 15)];
    atomicAdd(&stats4[tid], s);
  }
  __syncthreads();
  #pragma unroll
  for (int c=0;c<4;c++) red[c*256 + tid] = ssq[c];
  __syncthreads();
  if (tid < 64){
    int cc = tid >> 4;
    float s = 0.f;
    for (int g=0; g<16; g++) s += red[cc*256 + g*16 + (tid & 15)];
    atomicAdd(&stats4[64+tid], s);
  }
}

// ---- residual + next-layer P,Q (MFMA, swapped operands, fp16 out) ----
__global__ __launch_bounds__(256) void k_res_pq(float* __restrict__ h, const float* __restrict__ tn,
    const float* __restrict__ g4, const float* __restrict__ be4, const float* __restrict__ stats4,
    const float* __restrict__ A, const float* __restrict__ B,
    u16* __restrict__ P, u16* __restrict__ Q, int N, float invN){
  __shared__ _Float16 yL[64][72];
  __shared__ _Float16 wLa[64][72];
  __shared__ _Float16 wLb[64][72];
  __shared__ float scS[64], shS[64];
  int tid = threadIdx.x;
  if (tid < 64){
    float m = stats4[tid]*invN;
    float v = stats4[64+tid]*invN - m*m;
    float sc = g4[tid]*rsqrtf(v+EPS);
    scS[tid] = sc; shS[tid] = be4[tid] - m*sc;
  }
  for (int i = tid; i < 4096; i += 256){
    int k = i >> 6, n = i & 63;
    wLa[n][k] = (_Float16)A[i];
    wLb[n][k] = (_Float16)B[i];
  }
  __syncthreads();
  int row0 = blockIdx.x * 64;
  int srow = tid >> 2, sc0 = (tid & 3) * 16;
  {
    int row = row0 + srow;
    if (row < N){
      #pragma unroll
      for (int c=0;c<4;c++){
        int d0 = sc0 + 4*c;
        float4 hv4 = *(const float4*)(h + (size_t)row*64 + d0);
        float4 tv4 = *(const float4*)(tn + (size_t)row*64 + d0);
        float h0 = hv4.x + fmaxf(tv4.x*scS[d0  ] + shS[d0  ], 0.f);
        float h1 = hv4.y + fmaxf(tv4.y*scS[d0+1] + shS[d0+1], 0.f);
        float h2 = hv4.z + fmaxf(tv4.z*scS[d0+2] + shS[d0+2], 0.f);
        float h3 = hv4.w + fmaxf(tv4.w*scS[d0+3] + shS[d0+3], 0.f);
        *(float4*)(h + (size_t)row*64 + d0) = make_float4(h0,h1,h2,h3);
        *(u32*)&yL[srow][d0]   = pkh(h0, h1);
        *(u32*)&yL[srow][d0+2] = pkh(h2, h3);
      }
    } else {
      #pragma unroll
      for (int c=0;c<4;c++){
        *(u32*)&yL[srow][sc0+4*c] = 0u; *(u32*)&yL[srow][sc0+4*c+2] = 0u;
      }
    }
  }
  __syncthreads();
  int lane = tid & 63, wv = tid >> 6;
  int arow = lane & 15, kgrp = lane >> 4;
  f16x8 y0 = *(const f16x8*)&yL[16*wv + arow][8*kgrp];
  f16x8 y1 = *(const f16x8*)&yL[16*wv + arow][32 + 8*kgrp];
  int node = row0 + 16*wv + arow;
  #pragma unroll
  for (int c=0;c<4;c++){
    f16x8 wa0 = *(const f16x8*)&wLa[16*c + arow][8*kgrp];
    f16x8 wa1 = *(const f16x8*)&wLa[16*c + arow][32 + 8*kgrp];
    f32x4 dp = {0.f,0.f,0.f,0.f};
    dp = __builtin_amdgcn_mfma_f32_16x16x32_f16(wa0, y0, dp, 0, 0, 0);
    dp = __builtin_amdgcn_mfma_f32_16x16x32_f16(wa1, y1, dp, 0, 0, 0);
    f16x8 wb0 = *(const f16x8*)&wLb[16*c + arow][8*kgrp];
    f16x8 wb1 = *(const f16x8*)&wLb[16*c + arow][32 + 8*kgrp];
    f32x4 dq = {0.f,0.f,0.f,0.f};
    dq = __builtin_amdgcn_mfma_f32_16x16x32_f16(wb0, y0, dq, 0, 0, 0);
    dq = __builtin_amdgcn_mfma_f32_16x16x32_f16(wb1, y1, dq, 0, 0, 0);
    if (node < N){
      ushort4 pk4, qk4;
      pk4.x = f2h(dp[0]); pk4.y = f2h(dp[1]); pk4.z = f2h(dp[2]); pk4.w = f2h(dp[3]);
      qk4.x = f2h(dq[0]); qk4.y = f2h(dq[1]); qk4.z = f2h(dq[2]); qk4.w = f2h(dq[3]);
      *(ushort4*)(P + (size_t)node*64 + 16*c + 4*kgrp) = pk4;
      *(ushort4*)(Q + (size_t)node*64 + 16*c + 4*kgrp) = qk4;
    }
  }
}

// ---- final: h += relu(bn4(tn)); out = relu(h@Wp+bp) @ Wo + bo ----
__global__ __launch_bounds__(256) void k_res_head(const float* __restrict__ h, const float* __restrict__ tn,
    const float* __restrict__ g4, const float* __restrict__ be4, const float* __restrict__ stats4,
    const float* __restrict__ Wp, const float* __restrict__ bp,
    const float* __restrict__ Wo, const float* __restrict__ bo,
    float* __restrict__ out, int N, float invN){
  __shared__ float hs[64][68];
  __shared__ float Wps[64][64];
  __shared__ float ps[64][68];
  __shared__ float Wos[64][16];
  __shared__ float scS[64], shS[64];
  int tid = threadIdx.x;
  if (tid < 64){
    float m = stats4[tid]*invN;
    float v = stats4[64+tid]*invN - m*m;
    float sc = g4[tid]*rsqrtf(v+EPS);
    scS[tid] = sc; shS[tid] = be4[tid] - m*sc;
  }
  for (int i=tid;i<4096;i+=256) Wps[i>>6][i&63] = Wp[i];
  for (int i=tid;i<1024;i+=256) Wos[i>>4][i&15] = Wo[i];
  int row0 = blockIdx.x*64;
  __syncthreads();
  for (int i = tid; i < 4096; i += 256){
    int r = i>>6, k = i&63; int row = row0+r;
    float hv = 0.f;
    if (row<N)
      hv = h[(size_t)row*64+k] + fmaxf(tn[(size_t)row*64+k]*scS[k] + shS[k], 0.f);
    hs[r][k] = hv;
  }
  __syncthreads();
  int rq = tid>>4, dq = tid&15;
  float4 b4 = *(const float4*)(bp + dq*4);
  float acc[4][4];
  #pragma unroll
  for (int j=0;j<4;j++){ acc[j][0]=b4.x; acc[j][1]=b4.y; acc[j][2]=b4.z; acc[j][3]=b4.w; }
  for (int k=0;k<64;k+=4){
    float4 hv[4];
    #pragma unroll
    for (int j=0;j<4;j++) hv[j] = *(const float4*)&hs[rq*4+j][k];
    #pragma unroll
    for (int kk=0;kk<4;kk++){
      float4 wv = *(const float4*)&Wps[k+kk][dq*4];
      #pragma unroll
      for (int j=0;j<4;j++){
        float v = ((const float*)&hv[j])[kk];
        acc[j][0]+=v*wv.x; acc[j][1]+=v*wv.y; acc[j][2]+=v*wv.z; acc[j][3]+=v*wv.w;
      }
    }
  }
  #pragma unroll
  for (int j=0;j<4;j++){
    *(float4*)&ps[rq*4+j][dq*4] = make_float4(fmaxf(acc[j][0],0.f), fmaxf(acc[j][1],0.f),
                                              fmaxf(acc[j][2],0.f), fmaxf(acc[j][3],0.f));
  }
  __syncthreads();
  int f = tid & 15;
  float bof = bo[f];
  float acc2[4] = {bof, bof, bof, bof};
  for (int k=0;k<64;k++){
    float wv = Wos[k][f];
    #pragma unroll
    for (int j=0;j<4;j++) acc2[j] += ps[rq*4+j][k]*wv;
  }
  #pragma unroll
  for (int j=0;j<4;j++){
    int row = row0 + rq*4 + j;
    if (row<N) out[(size_t)row*16 + f] = acc2[j];
  }
}

extern "C" void kernel_launch(void* const* d_in, const int* in_sizes, int n_in,
                              void* d_out, int out_size, void* d_ws, size_t ws_size,
                              hipStream_t stream){
  const float* x    = (const float*)d_in[0];
  const float* eatt = (const float*)d_in[1];
  const float* Win  = (const float*)d_in[2];
  const float* bin  = (const float*)d_in[3];
  const float* mW1  = (const float*)d_in[4];
  const float* mb1  = (const float*)d_in[5];
  const float* mg1  = (const float*)d_in[6];
  const float* mbe1 = (const float*)d_in[7];
  const float* mW2  = (const float*)d_in[8];
  const float* mb2  = (const float*)d_in[9];
  const float* mg2  = (const float*)d_in[10];
  const float* mbe2 = (const float*)d_in[11];
  const float* uW1  = (const float*)d_in[12];
  const float* ub1  = (const float*)d_in[13];
  const float* ug1  = (const float*)d_in[14];
  const float* ube1 = (const float*)d_in[15];
  const float* uW2  = (const float*)d_in[16];
  const float* ub2  = (const float*)d_in[17];
  const float* ug2  = (const float*)d_in[18];
  const float* ube2 = (const float*)d_in[19];
  const float* predW = (const float*)d_in[24];
  const float* predb = (const float*)d_in[25];
  const float* poutW = (const float*)d_in[26];
  const float* poutb = (const float*)d_in[27];
  const int*   ei    = (const int*)d_in[28];

  const int N = in_sizes[0] / 18;
  const int E = in_sizes[1];

  size_t nodeB = (size_t)N * 64 * sizeof(float);
  size_t halfB = (size_t)N * 64 * sizeof(u16);
  size_t t2B   = (size_t)E * 64 * sizeof(u16);
  size_t statsB = 16 * 128 * sizeof(float);
  int NB = (N + 1023)/1024;
  size_t csrB = (size_t)E*8 + (size_t)(N+1)*4 + (size_t)N*4 + (size_t)N*4 + 4096*4;

  bool planA = ws_size >= nodeB + 2*halfB + nodeB + t2B + csrB + statsB;

  char* w = (char*)d_ws;
  float* h = (float*)w; w += nodeB;
  u16* P = (u16*)w; w += halfB;
  u16* Q = (u16*)w; w += halfB;
  float* agg = (float*)w; w += nodeB;
  float* tn = agg;   // plan A: agg unused (fused); plan B: k_up1 reads agg block-locally then writes tn
  u16*  t2 = nullptr;
  int2* seS = nullptr;
  int *rp=nullptr, *cnt=nullptr, *wrp=nullptr, *bsum=nullptr;
  float* stats;
  if (planA){
    t2   = (u16*)w;  w += t2B;
    seS  = (int2*)w; w += (size_t)E*8;
    rp   = (int*)w;  w += (size_t)(N+1)*4;
    cnt  = (int*)w;  w += (size_t)N*4;
    wrp  = (int*)w;  w += (size_t)N*4;
    bsum = (int*)w;  w += 4096*4;
    stats = (float*)w;
  } else {
    stats = (float*)w;
  }

  hipMemsetAsync(stats, 0, statsB, stream);

  int nb = (N + 63)/64;
  float invE = 1.0f/(float)E, invN = 1.0f/(float)N;

  k_in<<<nb, 256, 0, stream>>>(x, Win, bin, h, N);
  k_pq<<<nb, 256, 0, stream>>>(h, mW1, mW1 + 4096, P, Q, N);

  if (planA){
    hipMemsetAsync(cnt, 0, (size_t)N*4, stream);
    k_hist<<<(E+255)/256, 256, 0, stream>>>(ei, cnt, E);
    k_scan_a<<<NB, 256, 0, stream>>>(cnt, rp, bsum, N);
    k_scan_b<<<1, 64, 0, stream>>>(bsum, NB);
    k_scan_c<<<NB, 256, 0, stream>>>(cnt, rp, wrp, bsum, N, E);
    k_perm<<<(E+255)/256, 256, 0, stream>>>(ei, eatt, wrp, seS, E);
  }

  for (int l = 0; l < 4; ++l){
    float* s1 = stats + (l*4+0)*128;
    float* s2 = stats + (l*4+1)*128;
    float* s3 = stats + (l*4+2)*128;
    float* s4 = stats + (l*4+3)*128;
    const float* A  = mW1 + (size_t)l*8256;
    const float* c1 = A + 8192;
    if (planA){
      k_t1s<<<2048, 256, 0, stream>>>(P, Q, seS, rp, c1, mb1 + l*64, t2, s1, N);
      k_m2s<<<2048, 256, 0, stream>>>(t2, mg1 + l*64, mbe1 + l*64, s1,
                                      mW2 + (size_t)l*4096, mb2 + l*64, s2, E, invE);
      k_aggup1<<<nb, 256, 0, stream>>>(h, t2, rp, mg2 + l*64, mbe2 + l*64, s2,
                                       uW1 + (size_t)l*8192, ub1 + l*64, tn, s3, N, invE);
    } else {
      k_s1<<<2048, 256, 0, stream>>>(P, Q, eatt, ei, c1, mb1 + l*64, s1, E);
      k_m2b<<<1024, 256, 0, stream>>>(P, Q, eatt, ei, c1, mb1 + l*64, mg1 + l*64, mbe1 + l*64,
                                      s1, mW2 + (size_t)l*4096, mb2 + l*64, s2, E, invE);
      hipMemsetAsync(agg, 0, nodeB, stream);
      k_sc_rec<<<1024, 256, 0, stream>>>(P, Q, eatt, ei, c1, mb1 + l*64, mg1 + l*64, mbe1 + l*64,
                                         s1, mW2 + (size_t)l*4096, mb2 + l*64,
                                         mg2 + l*64, mbe2 + l*64, s2, agg, E, invE);
      k_up1<<<nb, 256, 0, stream>>>(h, agg, uW1 + (size_t)l*8192, ub1 + l*64, tn, s3, N);
    }
    k_up2<<<nb, 256, 0, stream>>>(tn, ug1 + l*64, ube1 + l*64, s3, uW2 + (size_t)l*4096,
                                  ub2 + l*64, s4, N, invN);
    if (l < 3){
      const float* An = mW1 + (size_t)(l+1)*8256;
      k_res_pq<<<nb, 256, 0, stream>>>(h, tn, ug2 + l*64, ube2 + l*64, s4,
                                       An, An + 4096, P, Q, N, invN);
    } else {
      k_res_head<<<nb, 256, 0, stream>>>(h, tn, ug2 + l*64, ube2 + l*64, s4,
                                         predW, predb, poutW, poutb, (float*)d_out, N, invN);
    }
  }
}

// Round 13
// 1832.131 us; speedup vs baseline: 1.0511x; 1.0511x over previous
//
#include <hip/hip_runtime.h>
#include <hip/hip_fp16.h>

typedef unsigned short u16;
typedef unsigned int u32;
typedef __attribute__((ext_vector_type(8))) unsigned short us8;
typedef __attribute__((ext_vector_type(8))) _Float16 f16x8;
typedef __attribute__((ext_vector_type(4))) float f32x4;

#define EPS 1e-5f

__device__ __forceinline__ float h2f(u16 h){ __half v; *(u16*)&v = h; return __half2float(v); }
__device__ __forceinline__ u16 f2h(float f){ __half v = __float2half(f); return *(u16*)&v; }
__device__ __forceinline__ u32 pkh(float a, float b){ return (u32)f2h(a) | ((u32)f2h(b) << 16); }

// ---------------- input projection: h = x @ W_in + b_in ----------------
__global__ __launch_bounds__(256) void k_in(const float* __restrict__ x,
    const float* __restrict__ Win, const float* __restrict__ bin,
    float* __restrict__ h, int N){
  __shared__ float Ws[18][64];
  __shared__ float xs[64][20];
  int tid = threadIdx.x;
  for (int i = tid; i < 18*64; i += 256) Ws[i>>6][i&63] = Win[i];
  int row0 = blockIdx.x * 64;
  for (int i = tid; i < 64*18; i += 256){
    int r = i/18, k = i - r*18;
    int row = row0 + r;
    xs[r][k] = (row < N) ? x[(size_t)row*18 + k] : 0.f;
  }
  __syncthreads();
  int rq = tid >> 4, dq = tid & 15;
  float4 b4 = *(const float4*)(bin + dq*4);
  float acc[4][4];
  #pragma unroll
  for (int j=0;j<4;j++){ acc[j][0]=b4.x; acc[j][1]=b4.y; acc[j][2]=b4.z; acc[j][3]=b4.w; }
  for (int k=0;k<18;k++){
    float4 wv = *(const float4*)&Ws[k][dq*4];
    #pragma unroll
    for (int j=0;j<4;j++){
      float v = xs[rq*4+j][k];
      acc[j][0]+=v*wv.x; acc[j][1]+=v*wv.y; acc[j][2]+=v*wv.z; acc[j][3]+=v*wv.w;
    }
  }
  #pragma unroll
  for (int j=0;j<4;j++){
    int row = row0 + rq*4 + j;
    if (row < N)
      *(float4*)(h + (size_t)row*64 + dq*4) = make_float4(acc[j][0],acc[j][1],acc[j][2],acc[j][3]);
  }
}

// ---------------- P = h@A, Q = h@B (fp16 out) ----------------
__global__ __launch_bounds__(256) void k_pq(const float* __restrict__ h,
    const float* __restrict__ A, const float* __restrict__ B,
    u16* __restrict__ P, u16* __restrict__ Q, int N){
  __shared__ float hs[64][68];
  __shared__ float As[64][64];
  __shared__ float Bs[64][64];
  int tid = threadIdx.x;
  for (int i = tid; i < 4096; i += 256){ As[i>>6][i&63] = A[i]; Bs[i>>6][i&63] = B[i]; }
  int row0 = blockIdx.x*64;
  for (int i = tid; i < 4096; i += 256){
    int r = i>>6, k = i&63; int row = row0+r;
    hs[r][k] = (row<N)? h[(size_t)row*64+k] : 0.f;
  }
  __syncthreads();
  int rq = tid>>4, dq = tid&15;
  float ap[4][4]={}, aq[4][4]={};
  for (int k=0;k<64;k+=4){
    float4 hv[4];
    #pragma unroll
    for (int j=0;j<4;j++) hv[j] = *(const float4*)&hs[rq*4+j][k];
    #pragma unroll
    for (int kk=0;kk<4;kk++){
      float4 av = *(const float4*)&As[k+kk][dq*4];
      float4 bv = *(const float4*)&Bs[k+kk][dq*4];
      #pragma unroll
      for (int j=0;j<4;j++){
        float v = ((const float*)&hv[j])[kk];
        ap[j][0]+=v*av.x; ap[j][1]+=v*av.y; ap[j][2]+=v*av.z; ap[j][3]+=v*av.w;
        aq[j][0]+=v*bv.x; aq[j][1]+=v*bv.y; aq[j][2]+=v*bv.z; aq[j][3]+=v*bv.w;
      }
    }
  }
  #pragma unroll
  for (int j=0;j<4;j++){
    int row = row0 + rq*4 + j;
    if (row<N){
      ushort4 pk, qk;
      pk.x=f2h(ap[j][0]); pk.y=f2h(ap[j][1]); pk.z=f2h(ap[j][2]); pk.w=f2h(ap[j][3]);
      qk.x=f2h(aq[j][0]); qk.y=f2h(aq[j][1]); qk.z=f2h(aq[j][2]); qk.w=f2h(aq[j][3]);
      *(ushort4*)(P+(size_t)row*64+dq*4) = pk;
      *(ushort4*)(Q+(size_t)row*64+dq*4) = qk;
    }
  }
}

// ================= CSR build (once, reused all 4 layers) =================
__global__ __launch_bounds__(256) void k_hist(const int* __restrict__ ei, int* __restrict__ cnt, int E){
  int e = blockIdx.x*256 + threadIdx.x;
  if (e < E) atomicAdd(&cnt[ei[E+e]], 1);
}

__global__ __launch_bounds__(256) void k_scan_a(const int* __restrict__ cnt, int* __restrict__ rp,
    int* __restrict__ bsum, int N){
  __shared__ int sm[256];
  int tid = threadIdx.x;
  int i0 = blockIdx.x*1024 + tid*4;
  int v0 = (i0+0<N)? cnt[i0+0]:0;
  int v1 = (i0+1<N)? cnt[i0+1]:0;
  int v2 = (i0+2<N)? cnt[i0+2]:0;
  int v3 = (i0+3<N)? cnt[i0+3]:0;
  int s = v0+v1+v2+v3;
  sm[tid] = s; __syncthreads();
  for (int ofs=1; ofs<256; ofs<<=1){
    int v = sm[tid];
    if (tid >= ofs) v += sm[tid-ofs];
    __syncthreads(); sm[tid] = v; __syncthreads();
  }
  int base = sm[tid] - s;
  int a0 = base+v0, a1 = a0+v1, a2 = a1+v2, a3 = a2+v3;
  if (i0+0<N) rp[i0+0]=a0;
  if (i0+1<N) rp[i0+1]=a1;
  if (i0+2<N) rp[i0+2]=a2;
  if (i0+3<N) rp[i0+3]=a3;
  if (tid==255) bsum[blockIdx.x] = sm[255];
}

__global__ void k_scan_b(int* __restrict__ bsum, int NB){
  if (threadIdx.x==0){
    int run = 0;
    for (int b=0;b<NB;b++){ int t = bsum[b]; bsum[b] = run; run += t; }
  }
}

__global__ __launch_bounds__(256) void k_scan_c(const int* __restrict__ cnt, int* __restrict__ rp,
    int* __restrict__ wr, const int* __restrict__ bsum, int N, int E){
  int tid = threadIdx.x;
  int i0 = blockIdx.x*1024 + tid*4;
  int off = bsum[blockIdx.x];
  #pragma unroll
  for (int j=0;j<4;j++){
    int i = i0+j;
    if (i<N){ int ex = off + rp[i] - cnt[i]; rp[i] = ex; wr[i] = ex; }
  }
  if (blockIdx.x==0 && tid==0) rp[N] = E;
}

// sorted packed array: seS[pos] = {src, edge_attr_bits}, pos in dst-sorted order
__global__ __launch_bounds__(256) void k_perm(const int* __restrict__ ei, const float* __restrict__ ea,
    int* __restrict__ wr, int2* __restrict__ seS, int E){
  int e = blockIdx.x*256 + threadIdx.x;
  if (e < E){
    int dn = ei[E+e];
    int pos = atomicAdd(&wr[dn], 1);
    seS[pos] = make_int2(ei[e], __float_as_int(ea[e]));
  }
}

// ------- node-centric gather (2 edge streams/wave, ushort2/lane): t + BN1 stats -------
__global__ __launch_bounds__(256) void k_t1s(const u16* __restrict__ P, const u16* __restrict__ Q,
    const int2* __restrict__ seS, const int* __restrict__ rp,
    const float* __restrict__ c1, const float* __restrict__ b1,
    u16* __restrict__ t, float* __restrict__ stats, int N){
  int tid = threadIdx.x;
  int lane = tid & 63, w = tid >> 6;
  int sub = lane >> 5;
  int dl = (lane & 31) * 2;
  float cv0 = c1[dl], cv1 = c1[dl+1];
  float bv0 = b1[dl], bv1 = b1[dl+1];
  float s0 = 0.f, s1 = 0.f, qs0 = 0.f, qs1 = 0.f;
  for (int n = blockIdx.x*4 + w; n < N; n += gridDim.x*4){
    int a = rp[n], b = rp[n+1];
    u32 pp = *(const u32*)(P + (size_t)n*64 + dl);
    float p0 = h2f((u16)(pp & 0xffffu)) + bv0;
    float p1 = h2f((u16)(pp >> 16)) + bv1;
    int p = a + sub;
    for (; p + 2 < b; p += 4){
      int2 seA = seS[p];
      int2 seB = seS[p+2];
      u32 qA = *(const u32*)(Q + (size_t)seA.x*64 + dl);
      u32 qB = *(const u32*)(Q + (size_t)seB.x*64 + dl);
      float eaA = __int_as_float(seA.y), eaB = __int_as_float(seB.y);
      float tA0 = p0 + h2f((u16)(qA & 0xffffu)) + eaA*cv0;
      float tA1 = p1 + h2f((u16)(qA >> 16)) + eaA*cv1;
      float tB0 = p0 + h2f((u16)(qB & 0xffffu)) + eaB*cv0;
      float tB1 = p1 + h2f((u16)(qB >> 16)) + eaB*cv1;
      *(u32*)(t + (size_t)p*64 + dl) = (u32)f2h(tA0) | ((u32)f2h(tA1) << 16);
      *(u32*)(t + (size_t)(p+2)*64 + dl) = (u32)f2h(tB0) | ((u32)f2h(tB1) << 16);
      s0 += tA0 + tB0; s1 += tA1 + tB1;
      qs0 += tA0*tA0 + tB0*tB0; qs1 += tA1*tA1 + tB1*tB1;
    }
    for (; p < b; p += 2){
      int2 se = seS[p];
      u32 qq = *(const u32*)(Q + (size_t)se.x*64 + dl);
      float ea = __int_as_float(se.y);
      float t0 = p0 + h2f((u16)(qq & 0xffffu)) + ea*cv0;
      float t1 = p1 + h2f((u16)(qq >> 16)) + ea*cv1;
      *(u32*)(t + (size_t)p*64 + dl) = (u32)f2h(t0) | ((u32)f2h(t1) << 16);
      s0 += t0; s1 += t1; qs0 += t0*t0; qs1 += t1*t1;
    }
  }
  __shared__ float sS[8][64], qS[8][64];
  int idx = w*2 + sub;
  sS[idx][dl] = s0; sS[idx][dl+1] = s1;
  qS[idx][dl] = qs0; qS[idx][dl+1] = qs1;
  __syncthreads();
  if (tid < 64){
    float ts = 0.f, tq = 0.f;
    #pragma unroll
    for (int r=0;r<8;r++){ ts += sS[r][tid]; tq += qS[r][tid]; }
    atomicAdd(&stats[tid], ts);
    atomicAdd(&stats[64+tid], tq);
  }
}

// ---- msg layer2 (MFMA, pipelined 128-edge tiles, swapped-operand epilogue) ----
__global__ __launch_bounds__(256) void k_m2s(u16* __restrict__ t,
    const float* __restrict__ g1, const float* __restrict__ be1, const float* __restrict__ stats1,
    const float* __restrict__ W2, const float* __restrict__ b2,
    float* __restrict__ stats2, int E, float invE){
  __shared__ _Float16 yL[128][72];
  __shared__ _Float16 wL[64][72];
  __shared__ float scS[64], shS[64], b2S[64];
  int tid = threadIdx.x;
  if (tid < 64){
    float m = stats1[tid]*invE;
    float v = stats1[64+tid]*invE - m*m;
    float sc = g1[tid]*rsqrtf(v + EPS);
    scS[tid] = sc; shS[tid] = be1[tid] - m*sc;
    b2S[tid] = b2[tid];
  }
  for (int i = tid; i < 4096; i += 256){
    int k = i >> 6, n = i & 63;
    wL[n][k] = (_Float16)W2[i];
  }
  __syncthreads();
  int lane = tid & 63, wv = tid >> 6;
  int arow = lane & 15;
  int kgrp = lane >> 4;
  int srow = tid >> 1, sc0 = (tid & 1)*32;
  float bb[4][4];
  #pragma unroll
  for (int c=0;c<4;c++){
    #pragma unroll
    for (int r=0;r<4;r++) bb[c][r] = b2S[16*c + 4*kgrp + r];
  }
  float ssum[4][4] = {}, ssq[4][4] = {};
  int ntiles = (E + 127) >> 7;
  f16x8 ra, rb, rc, rd;
  {
    f16x8 z;
    #pragma unroll
    for (int j=0;j<8;j++) z[j] = (_Float16)0.f;
    ra = rb = rc = rd = z;
    int tile = blockIdx.x;
    int p = tile*128 + srow;
    if (tile < ntiles && p < E){
      const u16* src = t + (size_t)p*64 + sc0;
      ra = *(const f16x8*)(src);
      rb = *(const f16x8*)(src + 8);
      rc = *(const f16x8*)(src + 16);
      rd = *(const f16x8*)(src + 24);
    }
  }
  for (int tile = blockIdx.x; tile < ntiles; tile += gridDim.x){
    int e0 = tile << 7;
    {
      f16x8 v;
      #pragma unroll
      for (int j=0;j<8;j++){ int dd = sc0 + j;      v[j] = (_Float16)fmaxf((float)ra[j]*scS[dd] + shS[dd], 0.f); }
      *(f16x8*)&yL[srow][sc0]      = v;
      #pragma unroll
      for (int j=0;j<8;j++){ int dd = sc0 + 8 + j;  v[j] = (_Float16)fmaxf((float)rb[j]*scS[dd] + shS[dd], 0.f); }
      *(f16x8*)&yL[srow][sc0 + 8]  = v;
      #pragma unroll
      for (int j=0;j<8;j++){ int dd = sc0 + 16 + j; v[j] = (_Float16)fmaxf((float)rc[j]*scS[dd] + shS[dd], 0.f); }
      *(f16x8*)&yL[srow][sc0 + 16] = v;
      #pragma unroll
      for (int j=0;j<8;j++){ int dd = sc0 + 24 + j; v[j] = (_Float16)fmaxf((float)rd[j]*scS[dd] + shS[dd], 0.f); }
      *(f16x8*)&yL[srow][sc0 + 24] = v;
    }
    {
      int nt = tile + gridDim.x;
      if (nt < ntiles){
        int p = nt*128 + srow;
        if (p < E){
          const u16* src = t + (size_t)p*64 + sc0;
          ra = *(const f16x8*)(src);
          rb = *(const f16x8*)(src + 8);
          rc = *(const f16x8*)(src + 16);
          rd = *(const f16x8*)(src + 24);
        } else {
          f16x8 z;
          #pragma unroll
          for (int j=0;j<8;j++) z[j] = (_Float16)0.f;
          ra = rb = rc = rd = z;
        }
      }
    }
    __syncthreads();
    #pragma unroll
    for (int mf=0; mf<2; mf++){
      int row = 32*wv + 16*mf + arow;
      f16x8 y0 = *(const f16x8*)&yL[row][8*kgrp];
      f16x8 y1 = *(const f16x8*)&yL[row][32 + 8*kgrp];
      int e = e0 + 32*wv + 16*mf + arow;
      #pragma unroll
      for (int c=0;c<4;c++){
        f16x8 w0 = *(const f16x8*)&wL[16*c + arow][8*kgrp];
        f16x8 w1 = *(const f16x8*)&wL[16*c + arow][32 + 8*kgrp];
        f32x4 d = {0.f,0.f,0.f,0.f};
        d = __builtin_amdgcn_mfma_f32_16x16x32_f16(w0, y0, d, 0, 0, 0);
        d = __builtin_amdgcn_mfma_f32_16x16x32_f16(w1, y1, d, 0, 0, 0);
        if (e < E){
          float v0 = d[0] + bb[c][0];
          float v1 = d[1] + bb[c][1];
          float v2 = d[2] + bb[c][2];
          float v3 = d[3] + bb[c][3];
          ushort4 st;
          st.x = f2h(v0); st.y = f2h(v1); st.z = f2h(v2); st.w = f2h(v3);
          *(ushort4*)(t + (size_t)e*64 + 16*c + 4*kgrp) = st;
          ssum[c][0]+=v0; ssum[c][1]+=v1; ssum[c][2]+=v2; ssum[c][3]+=v3;
          ssq[c][0]+=v0*v0; ssq[c][1]+=v1*v1; ssq[c][2]+=v2*v2; ssq[c][3]+=v3*v3;
        }
      }
    }
    __syncthreads();
  }
  float* red = (float*)yL;
  int slot = wv*16 + arow;
  #pragma unroll
  for (int c=0;c<4;c++){
    #pragma unroll
    for (int r=0;r<4;r++)
      red[(16*c + 4*kgrp + r)*64 + slot] = ssum[c][r];
  }
  __syncthreads();
  if (tid < 64){
    float s = 0.f;
    for (int g=0; g<64; g++) s += red[tid*64 + g];
    atomicAdd(&stats2[tid], s);
  }
  __syncthreads();
  #pragma unroll
  for (int c=0;c<4;c++){
    #pragma unroll
    for (int r=0;r<4;r++)
      red[(16*c + 4*kgrp + r)*64 + slot] = ssq[c][r];
  }
  __syncthreads();
  if (tid < 64){
    float s = 0.f;
    for (int g=0; g<64; g++) s += red[tid*64 + g];
    atomicAdd(&stats2[64+tid], s);
  }
}

// ---- segment-sum aggregation (fp16 out, 2 row streams/wave, no atomics) ----
__global__ __launch_bounds__(256) void k_agg(const u16* __restrict__ t2, const int* __restrict__ rp,
    const float* __restrict__ g2, const float* __restrict__ be2, const float* __restrict__ stats2,
    u16* __restrict__ aggh, int N, float invE){
  __shared__ float scS[64], shS[64];
  int tid = threadIdx.x;
  if (tid < 64){
    float m = stats2[tid]*invE;
    float v = stats2[64+tid]*invE - m*m;
    float sc = g2[tid]*rsqrtf(v+EPS);
    scS[tid] = sc; shS[tid] = be2[tid] - m*sc;
  }
  __syncthreads();
  int lane = tid & 63, w = tid >> 6;
  int sub = lane >> 5;
  int dl = (lane & 31) * 2;
  float sc0 = scS[dl], sc1 = scS[dl+1], sh0 = shS[dl], sh1 = shS[dl+1];
  for (int n = blockIdx.x*4 + w; n < N; n += gridDim.x*4){
    int a = rp[n], b = rp[n+1];
    float a0 = 0.f, a1 = 0.f;
    int p = a + sub;
    for (; p + 2 < b; p += 4){
      u32 vA = *(const u32*)(t2 + (size_t)p*64 + dl);
      u32 vB = *(const u32*)(t2 + (size_t)(p+2)*64 + dl);
      a0 += fmaxf(h2f((u16)(vA & 0xffffu))*sc0 + sh0, 0.f)
          + fmaxf(h2f((u16)(vB & 0xffffu))*sc0 + sh0, 0.f);
      a1 += fmaxf(h2f((u16)(vA >> 16))*sc1 + sh1, 0.f)
          + fmaxf(h2f((u16)(vB >> 16))*sc1 + sh1, 0.f);
    }
    for (; p < b; p += 2){
      u32 vA = *(const u32*)(t2 + (size_t)p*64 + dl);
      a0 += fmaxf(h2f((u16)(vA & 0xffffu))*sc0 + sh0, 0.f);
      a1 += fmaxf(h2f((u16)(vA >> 16))*sc1 + sh1, 0.f);
    }
    a0 += __shfl_xor(a0, 32);
    a1 += __shfl_xor(a1, 32);
    if (sub == 0)
      *(u32*)(aggh + (size_t)n*64 + dl) = pkh(a0, a1);
  }
}

// ======== Plan-B fallback (small ws): stats pass + recompute scatter ========
__global__ __launch_bounds__(256) void k_s1(const u16* __restrict__ P, const u16* __restrict__ Q,
    const float* __restrict__ ea, const int* __restrict__ ei,
    const float* __restrict__ c1, const float* __restrict__ b1,
    float* __restrict__ stats, int E){
  int tid = threadIdx.x;
  int d = tid & 63, w = tid >> 6;
  float cv = c1[d], bv = b1[d];
  float s = 0.f, sq = 0.f;
  for (int e = blockIdx.x*4 + w; e < E; e += gridDim.x*4){
    int dn = ei[E+e], sn = ei[e];
    float t = h2f(P[(size_t)dn*64+d]) + h2f(Q[(size_t)sn*64+d]) + ea[e]*cv + bv;
    s += t; sq += t*t;
  }
  __shared__ float sS[4][64], qS[4][64];
  sS[w][d] = s; qS[w][d] = sq;
  __syncthreads();
  if (tid < 64){
    float ts = sS[0][tid]+sS[1][tid]+sS[2][tid]+sS[3][tid];
    float tq = qS[0][tid]+qS[1][tid]+qS[2][tid]+qS[3][tid];
    atomicAdd(&stats[tid], ts);
    atomicAdd(&stats[64+tid], tq);
  }
}

__global__ __launch_bounds__(256) void k_m2b(const u16* __restrict__ P, const u16* __restrict__ Q,
    const float* __restrict__ ea, const int* __restrict__ ei,
    const float* __restrict__ c1, const float* __restrict__ b1,
    const float* __restrict__ g1, const float* __restrict__ be1,
    const float* __restrict__ stats1,
    const float* __restrict__ W2, const float* __restrict__ b2,
    float* __restrict__ stats2, int E, float invE){
  __shared__ float ys[64][68];
  __shared__ float Ws[64][64];
  __shared__ float scS[64], c1S[64], bS[64], b2S[64];
  int tid = threadIdx.x;
  if (tid < 64){
    float m = stats1[tid]*invE;
    float v = stats1[64+tid]*invE - m*m;
    float sc = g1[tid]*rsqrtf(v + EPS);
    float sh = be1[tid] - m*sc;
    scS[tid] = sc;
    c1S[tid] = c1[tid]*sc;
    bS[tid]  = b1[tid]*sc + sh;
    b2S[tid] = b2[tid];
  }
  for (int i=tid;i<4096;i+=256) Ws[i>>6][i&63] = W2[i];
  __syncthreads();
  int rq = tid>>4, dq = tid&15;
  float ssum[4]={}, ssq[4]={};
  int ntiles = (E+63)>>6;
  for (int tile = blockIdx.x; tile < ntiles; tile += gridDim.x){
    int e0 = tile<<6;
    for (int i = tid; i < 4096; i += 256){
      int el = i>>6, dd = i&63;
      int e = e0 + el;
      float y = 0.f;
      if (e < E){
        int dn = ei[E+e], sn = ei[e];
        float t = (h2f(P[(size_t)dn*64+dd]) + h2f(Q[(size_t)sn*64+dd]))*scS[dd] + ea[e]*c1S[dd] + bS[dd];
        y = fmaxf(t, 0.f);
      }
      ys[el][dd] = y;
    }
    __syncthreads();
    float acc[4][4];
    float4 b4 = *(const float4*)&b2S[dq*4];
    #pragma unroll
    for (int j=0;j<4;j++){ acc[j][0]=b4.x; acc[j][1]=b4.y; acc[j][2]=b4.z; acc[j][3]=b4.w; }
    for (int k=0;k<64;k+=4){
      float4 hv[4];
      #pragma unroll
      for (int j=0;j<4;j++) hv[j] = *(const float4*)&ys[rq*4+j][k];
      #pragma unroll
      for (int kk=0;kk<4;kk++){
        float4 wv = *(const float4*)&Ws[k+kk][dq*4];
        #pragma unroll
        for (int j=0;j<4;j++){
          float v = ((const float*)&hv[j])[kk];
          acc[j][0]+=v*wv.x; acc[j][1]+=v*wv.y; acc[j][2]+=v*wv.z; acc[j][3]+=v*wv.w;
        }
      }
    }
    #pragma unroll
    for (int j=0;j<4;j++){
      int e = e0 + rq*4 + j;
      if (e < E){
        #pragma unroll
        for (int c=0;c<4;c++){ float v=acc[j][c]; ssum[c]+=v; ssq[c]+=v*v; }
      }
    }
    __syncthreads();
  }
  float* red = &ys[0][0];
  #pragma unroll
  for (int c=0;c<4;c++) red[rq*64 + dq*4 + c] = ssum[c];
  __syncthreads();
  if (tid < 64){
    float t=0.f;
    for (int r=0;r<16;r++) t += red[r*64+tid];
    atomicAdd(&stats2[tid], t);
  }
  __syncthreads();
  #pragma unroll
  for (int c=0;c<4;c++) red[rq*64 + dq*4 + c] = ssq[c];
  __syncthreads();
  if (tid < 64){
    float t=0.f;
    for (int r=0;r<16;r++) t += red[r*64+tid];
    atomicAdd(&stats2[64+tid], t);
  }
}

__global__ __launch_bounds__(256) void k_sc_rec(const u16* __restrict__ P, const u16* __restrict__ Q,
    const float* __restrict__ ea, const int* __restrict__ ei,
    const float* __restrict__ c1, const float* __restrict__ b1,
    const float* __restrict__ g1, const float* __restrict__ be1, const float* __restrict__ stats1,
    const float* __restrict__ W2, const float* __restrict__ b2,
    const float* __restrict__ g2, const float* __restrict__ be2, const float* __restrict__ stats2,
    float* __restrict__ agg, int E, float invE){
  __shared__ float ys[64][68];
  __shared__ float Ws[64][64];
  __shared__ float scS[64], c1S[64], bS[64];
  __shared__ float s2S[64], h2S[64], b2S[64];
  int tid = threadIdx.x;
  if (tid < 64){
    float m = stats1[tid]*invE;
    float v = stats1[64+tid]*invE - m*m;
    float sc = g1[tid]*rsqrtf(v + EPS);
    scS[tid] = sc;
    c1S[tid] = c1[tid]*sc;
    bS[tid]  = b1[tid]*sc + be1[tid] - m*sc;
    float m2 = stats2[tid]*invE;
    float v2 = stats2[64+tid]*invE - m2*m2;
    float sc2 = g2[tid]*rsqrtf(v2+EPS);
    s2S[tid] = sc2; h2S[tid] = be2[tid] - m2*sc2;
    b2S[tid] = b2[tid];
  }
  for (int i=tid;i<4096;i+=256) Ws[i>>6][i&63] = W2[i];
  __syncthreads();
  int rq = tid>>4, dq = tid&15;
  int ntiles = (E+63)>>6;
  for (int tile = blockIdx.x; tile < ntiles; tile += gridDim.x){
    int e0 = tile<<6;
    for (int i = tid; i < 4096; i += 256){
      int el = i>>6, dd = i&63;
      int e = e0 + el;
      float y = 0.f;
      if (e < E){
        int dn = ei[E+e], sn = ei[e];
        float t = (h2f(P[(size_t)dn*64+dd]) + h2f(Q[(size_t)sn*64+dd]))*scS[dd] + ea[e]*c1S[dd] + bS[dd];
        y = fmaxf(t, 0.f);
      }
      ys[el][dd] = y;
    }
    __syncthreads();
    float acc[4][4];
    float4 b4 = *(const float4*)&b2S[dq*4];
    #pragma unroll
    for (int j=0;j<4;j++){ acc[j][0]=b4.x; acc[j][1]=b4.y; acc[j][2]=b4.z; acc[j][3]=b4.w; }
    for (int k=0;k<64;k+=4){
      float4 hv[4];
      #pragma unroll
      for (int j=0;j<4;j++) hv[j] = *(const float4*)&ys[rq*4+j][k];
      #pragma unroll
      for (int kk=0;kk<4;kk++){
        float4 wv = *(const float4*)&Ws[k+kk][dq*4];
        #pragma unroll
        for (int j=0;j<4;j++){
          float v = ((const float*)&hv[j])[kk];
          acc[j][0]+=v*wv.x; acc[j][1]+=v*wv.y; acc[j][2]+=v*wv.z; acc[j][3]+=v*wv.w;
        }
      }
    }
    float4 sc4 = *(const float4*)&s2S[dq*4];
    float4 sh4 = *(const float4*)&h2S[dq*4];
    #pragma unroll
    for (int j=0;j<4;j++){
      int e = e0 + rq*4 + j;
      if (e < E){
        int dn = ei[E+e];
        float y0 = fmaxf(acc[j][0]*sc4.x + sh4.x, 0.f);
        float y1 = fmaxf(acc[j][1]*sc4.y + sh4.y, 0.f);
        float y2 = fmaxf(acc[j][2]*sc4.z + sh4.z, 0.f);
        float y3 = fmaxf(acc[j][3]*sc4.w + sh4.w, 0.f);
        atomicAdd(&agg[(size_t)dn*64 + dq*4    ], y0);
        atomicAdd(&agg[(size_t)dn*64 + dq*4 + 1], y1);
        atomicAdd(&agg[(size_t)dn*64 + dq*4 + 2], y2);
        atomicAdd(&agg[(size_t)dn*64 + dq*4 + 3], y3);
      }
    }
    __syncthreads();
  }
}

// ---- upd layer1, plan A (MFMA, K=128, fp16 agg): tn = [h,aggh] @ U1 + b + stats3 ----
__global__ __launch_bounds__(256) void k_up1h(const float* __restrict__ h, const u16* __restrict__ aggh,
    const float* __restrict__ U1, const float* __restrict__ b1u,
    float* __restrict__ tn, float* __restrict__ stats3, int N){
  __shared__ _Float16 yL[64][136];
  __shared__ _Float16 wL[64][136];
  __shared__ float bS[64];
  int tid = threadIdx.x;
  if (tid < 64) bS[tid] = b1u[tid];
  for (int i = tid; i < 8192; i += 256){
    int k = i >> 6, n = i & 63;
    wL[n][k] = (_Float16)U1[i];
  }
  int row0 = blockIdx.x * 64;
  int srow = tid >> 2, sc0 = (tid & 3) * 16;
  {
    int row = row0 + srow;
    if (row < N){
      #pragma unroll
      for (int c=0;c<4;c++){
        float4 v = *(const float4*)(h + (size_t)row*64 + sc0 + 4*c);
        *(u32*)&yL[srow][sc0+4*c]   = pkh(v.x, v.y);
        *(u32*)&yL[srow][sc0+4*c+2] = pkh(v.z, v.w);
      }
      const u16* srcA = aggh + (size_t)row*64 + sc0;
      *(f16x8*)&yL[srow][64+sc0]     = *(const f16x8*)(srcA);
      *(f16x8*)&yL[srow][64+sc0+8]   = *(const f16x8*)(srcA + 8);
    } else {
      #pragma unroll
      for (int c=0;c<4;c++){
        *(u32*)&yL[srow][sc0+4*c] = 0u; *(u32*)&yL[srow][sc0+4*c+2] = 0u;
        *(u32*)&yL[srow][64+sc0+4*c] = 0u; *(u32*)&yL[srow][64+sc0+4*c+2] = 0u;
      }
    }
  }
  __syncthreads();
  int lane = tid & 63, wv = tid >> 6;
  int arow = lane & 15, kgrp = lane >> 4;
  f16x8 a[4];
  #pragma unroll
  for (int kk=0;kk<4;kk++) a[kk] = *(const f16x8*)&yL[16*wv + arow][32*kk + 8*kgrp];
  float ssum[4]={}, ssq[4]={};
  #pragma unroll
  for (int c=0;c<4;c++){
    f32x4 d = {0.f,0.f,0.f,0.f};
    #pragma unroll
    for (int kk=0;kk<4;kk++){
      f16x8 b = *(const f16x8*)&wL[16*c + arow][32*kk + 8*kgrp];
      d = __builtin_amdgcn_mfma_f32_16x16x32_f16(a[kk], b, d, 0, 0, 0);
    }
    int col = 16*c + arow;
    float bb = bS[col];
    #pragma unroll
    for (int r=0;r<4;r++){
      int row = row0 + 16*wv + 4*kgrp + r;
      if (row < N){
        float v = d[r] + bb;
        tn[(size_t)row*64 + col] = v;
        ssum[c]+=v; ssq[c]+=v*v;
      }
    }
  }
  __syncthreads();
  float* red = (float*)yL;
  #pragma unroll
  for (int c=0;c<4;c++) red[c*256 + tid] = ssum[c];
  __syncthreads();
  if (tid < 64){
    int cc = tid >> 4;
    float s = 0.f;
    for (int g=0; g<16; g++) s += red[cc*256 + g*16 + (tid & 15)];
    atomicAdd(&stats3[tid], s);
  }
  __syncthreads();
  #pragma unroll
  for (int c=0;c<4;c++) red[c*256 + tid] = ssq[c];
  __syncthreads();
  if (tid < 64){
    int cc = tid >> 4;
    float s = 0.f;
    for (int g=0; g<16; g++) s += red[cc*256 + g*16 + (tid & 15)];
    atomicAdd(&stats3[64+tid], s);
  }
}

// ---- upd layer1, plan B (MFMA, K=128, fp32 agg): tn = [h,agg] @ U1 + b + stats3 ----
__global__ __launch_bounds__(256) void k_up1(const float* __restrict__ h, const float* __restrict__ agg,
    const float* __restrict__ U1, const float* __restrict__ b1u,
    float* __restrict__ tn, float* __restrict__ stats3, int N){
  __shared__ _Float16 yL[64][136];
  __shared__ _Float16 wL[64][136];
  __shared__ float bS[64];
  int tid = threadIdx.x;
  if (tid < 64) bS[tid] = b1u[tid];
  for (int i = tid; i < 8192; i += 256){
    int k = i >> 6, n = i & 63;
    wL[n][k] = (_Float16)U1[i];
  }
  int row0 = blockIdx.x * 64;
  int srow = tid >> 2, sc0 = (tid & 3) * 16;
  {
    int row = row0 + srow;
    if (row < N){
      #pragma unroll
      for (int c=0;c<4;c++){
        float4 v = *(const float4*)(h + (size_t)row*64 + sc0 + 4*c);
        *(u32*)&yL[srow][sc0+4*c]   = pkh(v.x, v.y);
        *(u32*)&yL[srow][sc0+4*c+2] = pkh(v.z, v.w);
      }
      #pragma unroll
      for (int c=0;c<4;c++){
        float4 v = *(const float4*)(agg + (size_t)row*64 + sc0 + 4*c);
        *(u32*)&yL[srow][64+sc0+4*c]   = pkh(v.x, v.y);
        *(u32*)&yL[srow][64+sc0+4*c+2] = pkh(v.z, v.w);
      }
    } else {
      #pragma unroll
      for (int c=0;c<4;c++){
        *(u32*)&yL[srow][sc0+4*c] = 0u; *(u32*)&yL[srow][sc0+4*c+2] = 0u;
        *(u32*)&yL[srow][64+sc0+4*c] = 0u; *(u32*)&yL[srow][64+sc0+4*c+2] = 0u;
      }
    }
  }
  __syncthreads();
  int lane = tid & 63, wv = tid >> 6;
  int arow = lane & 15, kgrp = lane >> 4;
  f16x8 a[4];
  #pragma unroll
  for (int kk=0;kk<4;kk++) a[kk] = *(const f16x8*)&yL[16*wv + arow][32*kk + 8*kgrp];
  float ssum[4]={}, ssq[4]={};
  #pragma unroll
  for (int c=0;c<4;c++){
    f32x4 d = {0.f,0.f,0.f,0.f};
    #pragma unroll
    for (int kk=0;kk<4;kk++){
      f16x8 b = *(const f16x8*)&wL[16*c + arow][32*kk + 8*kgrp];
      d = __builtin_amdgcn_mfma_f32_16x16x32_f16(a[kk], b, d, 0, 0, 0);
    }
    int col = 16*c + arow;
    float bb = bS[col];
    #pragma unroll
    for (int r=0;r<4;r++){
      int row = row0 + 16*wv + 4*kgrp + r;
      if (row < N){
        float v = d[r] + bb;
        tn[(size_t)row*64 + col] = v;
        ssum[c]+=v; ssq[c]+=v*v;
      }
    }
  }
  __syncthreads();
  float* red = (float*)yL;
  #pragma unroll
  for (int c=0;c<4;c++) red[c*256 + tid] = ssum[c];
  __syncthreads();
  if (tid < 64){
    int cc = tid >> 4;
    float s = 0.f;
    for (int g=0; g<16; g++) s += red[cc*256 + g*16 + (tid & 15)];
    atomicAdd(&stats3[tid], s);
  }
  __syncthreads();
  #pragma unroll
  for (int c=0;c<4;c++) red[c*256 + tid] = ssq[c];
  __syncthreads();
  if (tid < 64){
    int cc = tid >> 4;
    float s = 0.f;
    for (int g=0; g<16; g++) s += red[cc*256 + g*16 + (tid & 15)];
    atomicAdd(&stats3[64+tid], s);
  }
}

// ---- upd layer2 (MFMA, K=64): tn = relu(bn3(tn)) @ U2 + b2 (in place) + stats4 ----
__global__ __launch_bounds__(256) void k_up2(float* __restrict__ tn,
    const float* __restrict__ g3, const float* __restrict__ be3, const float* __restrict__ stats3,
    const float* __restrict__ U2, const float* __restrict__ b2u,
    float* __restrict__ stats4, int N, float invN){
  __shared__ _Float16 yL[64][72];
  __shared__ _Float16 wL[64][72];
  __shared__ float scS[64], shS[64], bS[64];
  int tid = threadIdx.x;
  if (tid < 64){
    float m = stats3[tid]*invN;
    float v = stats3[64+tid]*invN - m*m;
    float sc = g3[tid]*rsqrtf(v+EPS);
    scS[tid] = sc; shS[tid] = be3[tid] - m*sc; bS[tid] = b2u[tid];
  }
  for (int i = tid; i < 4096; i += 256){
    int k = i >> 6, n = i & 63;
    wL[n][k] = (_Float16)U2[i];
  }
  __syncthreads();
  int row0 = blockIdx.x * 64;
  int srow = tid >> 2, sc0 = (tid & 3) * 16;
  {
    int row = row0 + srow;
    if (row < N){
      #pragma unroll
      for (int c=0;c<4;c++){
        float4 v = *(const float4*)(tn + (size_t)row*64 + sc0 + 4*c);
        int d0 = sc0 + 4*c;
        float y0 = fmaxf(v.x*scS[d0  ] + shS[d0  ], 0.f);
        float y1 = fmaxf(v.y*scS[d0+1] + shS[d0+1], 0.f);
        float y2 = fmaxf(v.z*scS[d0+2] + shS[d0+2], 0.f);
        float y3 = fmaxf(v.w*scS[d0+3] + shS[d0+3], 0.f);
        *(u32*)&yL[srow][d0]   = pkh(y0, y1);
        *(u32*)&yL[srow][d0+2] = pkh(y2, y3);
      }
    } else {
      #pragma unroll
      for (int c=0;c<4;c++){
        *(u32*)&yL[srow][sc0+4*c] = 0u; *(u32*)&yL[srow][sc0+4*c+2] = 0u;
      }
    }
  }
  __syncthreads();
  int lane = tid & 63, wv = tid >> 6;
  int arow = lane & 15, kgrp = lane >> 4;
  f16x8 a0 = *(const f16x8*)&yL[16*wv + arow][8*kgrp];
  f16x8 a1 = *(const f16x8*)&yL[16*wv + arow][32 + 8*kgrp];
  float ssum[4]={}, ssq[4]={};
  #pragma unroll
  for (int c=0;c<4;c++){
    f16x8 b0 = *(const f16x8*)&wL[16*c + arow][8*kgrp];
    f16x8 b1 = *(const f16x8*)&wL[16*c + arow][32 + 8*kgrp];
    f32x4 d = {0.f,0.f,0.f,0.f};
    d = __builtin_amdgcn_mfma_f32_16x16x32_f16(a0, b0, d, 0, 0, 0);
    d = __builtin_amdgcn_mfma_f32_16x16x32_f16(a1, b1, d, 0, 0, 0);
    int col = 16*c + arow;
    float bb = bS[col];
    #pragma unroll
    for (int r=0;r<4;r++){
      int row = row0 + 16*wv + 4*kgrp + r;
      if (row < N){
        float v = d[r] + bb;
        tn[(size_t)row*64 + col] = v;
        ssum[c]+=v; ssq[c]+=v*v;
      }
    }
  }
  __syncthreads();
  float* red = (float*)yL;
  #pragma unroll
  for (int c=0;c<4;c++) red[c*256 + tid] = ssum[c];
  __syncthreads();
  if (tid < 64){
    int cc = tid >> 4;
    float s = 0.f;
    for (int g=0; g<16; g++) s += red[cc*256 + g*16 + (tid & 15)];
    atomicAdd(&stats4[tid], s);
  }
  __syncthreads();
  #pragma unroll
  for (int c=0;c<4;c++) red[c*256 + tid] = ssq[c];
  __syncthreads();
  if (tid < 64){
    int cc = tid >> 4;
    float s = 0.f;
    for (int g=0; g<16; g++) s += red[cc*256 + g*16 + (tid & 15)];
    atomicAdd(&stats4[64+tid], s);
  }
}

// ---- residual + next-layer P,Q (MFMA, swapped operands, fp16 out) ----
__global__ __launch_bounds__(256) void k_res_pq(float* __restrict__ h, const float* __restrict__ tn,
    const float* __restrict__ g4, const float* __restrict__ be4, const float* __restrict__ stats4,
    const float* __restrict__ A, const float* __restrict__ B,
    u16* __restrict__ P, u16* __restrict__ Q, int N, float invN){
  __shared__ _Float16 yL[64][72];
  __shared__ _Float16 wLa[64][72];
  __shared__ _Float16 wLb[64][72];
  __shared__ float scS[64], shS[64];
  int tid = threadIdx.x;
  if (tid < 64){
    float m = stats4[tid]*invN;
    float v = stats4[64+tid]*invN - m*m;
    float sc = g4[tid]*rsqrtf(v+EPS);
    scS[tid] = sc; shS[tid] = be4[tid] - m*sc;
  }
  for (int i = tid; i < 4096; i += 256){
    int k = i >> 6, n = i & 63;
    wLa[n][k] = (_Float16)A[i];
    wLb[n][k] = (_Float16)B[i];
  }
  __syncthreads();
  int row0 = blockIdx.x * 64;
  int srow = tid >> 2, sc0 = (tid & 3) * 16;
  {
    int row = row0 + srow;
    if (row < N){
      #pragma unroll
      for (int c=0;c<4;c++){
        int d0 = sc0 + 4*c;
        float4 hv4 = *(const float4*)(h + (size_t)row*64 + d0);
        float4 tv4 = *(const float4*)(tn + (size_t)row*64 + d0);
        float h0 = hv4.x + fmaxf(tv4.x*scS[d0  ] + shS[d0  ], 0.f);
        float h1 = hv4.y + fmaxf(tv4.y*scS[d0+1] + shS[d0+1], 0.f);
        float h2 = hv4.z + fmaxf(tv4.z*scS[d0+2] + shS[d0+2], 0.f);
        float h3 = hv4.w + fmaxf(tv4.w*scS[d0+3] + shS[d0+3], 0.f);
        *(float4*)(h + (size_t)row*64 + d0) = make_float4(h0,h1,h2,h3);
        *(u32*)&yL[srow][d0]   = pkh(h0, h1);
        *(u32*)&yL[srow][d0+2] = pkh(h2, h3);
      }
    } else {
      #pragma unroll
      for (int c=0;c<4;c++){
        *(u32*)&yL[srow][sc0+4*c] = 0u; *(u32*)&yL[srow][sc0+4*c+2] = 0u;
      }
    }
  }
  __syncthreads();
  int lane = tid & 63, wv = tid >> 6;
  int arow = lane & 15, kgrp = lane >> 4;
  f16x8 y0 = *(const f16x8*)&yL[16*wv + arow][8*kgrp];
  f16x8 y1 = *(const f16x8*)&yL[16*wv + arow][32 + 8*kgrp];
  int node = row0 + 16*wv + arow;
  #pragma unroll
  for (int c=0;c<4;c++){
    f16x8 wa0 = *(const f16x8*)&wLa[16*c + arow][8*kgrp];
    f16x8 wa1 = *(const f16x8*)&wLa[16*c + arow][32 + 8*kgrp];
    f32x4 dp = {0.f,0.f,0.f,0.f};
    dp = __builtin_amdgcn_mfma_f32_16x16x32_f16(wa0, y0, dp, 0, 0, 0);
    dp = __builtin_amdgcn_mfma_f32_16x16x32_f16(wa1, y1, dp, 0, 0, 0);
    f16x8 wb0 = *(const f16x8*)&wLb[16*c + arow][8*kgrp];
    f16x8 wb1 = *(const f16x8*)&wLb[16*c + arow][32 + 8*kgrp];
    f32x4 dq = {0.f,0.f,0.f,0.f};
    dq = __builtin_amdgcn_mfma_f32_16x16x32_f16(wb0, y0, dq, 0, 0, 0);
    dq = __builtin_amdgcn_mfma_f32_16x16x32_f16(wb1, y1, dq, 0, 0, 0);
    if (node < N){
      ushort4 pk4, qk4;
      pk4.x = f2h(dp[0]); pk4.y = f2h(dp[1]); pk4.z = f2h(dp[2]); pk4.w = f2h(dp[3]);
      qk4.x = f2h(dq[0]); qk4.y = f2h(dq[1]); qk4.z = f2h(dq[2]); qk4.w = f2h(dq[3]);
      *(ushort4*)(P + (size_t)node*64 + 16*c + 4*kgrp) = pk4;
      *(ushort4*)(Q + (size_t)node*64 + 16*c + 4*kgrp) = qk4;
    }
  }
}

// ---- final: h += relu(bn4(tn)); out = relu(h@Wp+bp) @ Wo + bo ----
__global__ __launch_bounds__(256) void k_res_head(const float* __restrict__ h, const float* __restrict__ tn,
    const float* __restrict__ g4, const float* __restrict__ be4, const float* __restrict__ stats4,
    const float* __restrict__ Wp, const float* __restrict__ bp,
    const float* __restrict__ Wo, const float* __restrict__ bo,
    float* __restrict__ out, int N, float invN){
  __shared__ float hs[64][68];
  __shared__ float Wps[64][64];
  __shared__ float ps[64][68];
  __shared__ float Wos[64][16];
  __shared__ float scS[64], shS[64];
  int tid = threadIdx.x;
  if (tid < 64){
    float m = stats4[tid]*invN;
    float v = stats4[64+tid]*invN - m*m;
    float sc = g4[tid]*rsqrtf(v+EPS);
    scS[tid] = sc; shS[tid] = be4[tid] - m*sc;
  }
  for (int i=tid;i<4096;i+=256) Wps[i>>6][i&63] = Wp[i];
  for (int i=tid;i<1024;i+=256) Wos[i>>4][i&15] = Wo[i];
  int row0 = blockIdx.x*64;
  __syncthreads();
  for (int i = tid; i < 4096; i += 256){
    int r = i>>6, k = i&63; int row = row0+r;
    float hv = 0.f;
    if (row<N)
      hv = h[(size_t)row*64+k] + fmaxf(tn[(size_t)row*64+k]*scS[k] + shS[k], 0.f);
    hs[r][k] = hv;
  }
  __syncthreads();
  int rq = tid>>4, dq = tid&15;
  float4 b4 = *(const float4*)(bp + dq*4);
  float acc[4][4];
  #pragma unroll
  for (int j=0;j<4;j++){ acc[j][0]=b4.x; acc[j][1]=b4.y; acc[j][2]=b4.z; acc[j][3]=b4.w; }
  for (int k=0;k<64;k+=4){
    float4 hv[4];
    #pragma unroll
    for (int j=0;j<4;j++) hv[j] = *(const float4*)&hs[rq*4+j][k];
    #pragma unroll
    for (int kk=0;kk<4;kk++){
      float4 wv = *(const float4*)&Wps[k+kk][dq*4];
      #pragma unroll
      for (int j=0;j<4;j++){
        float v = ((const float*)&hv[j])[kk];
        acc[j][0]+=v*wv.x; acc[j][1]+=v*wv.y; acc[j][2]+=v*wv.z; acc[j][3]+=v*wv.w;
      }
    }
  }
  #pragma unroll
  for (int j=0;j<4;j++){
    *(float4*)&ps[rq*4+j][dq*4] = make_float4(fmaxf(acc[j][0],0.f), fmaxf(acc[j][1],0.f),
                                              fmaxf(acc[j][2],0.f), fmaxf(acc[j][3],0.f));
  }
  __syncthreads();
  int f = tid & 15;
  float bof = bo[f];
  float acc2[4] = {bof, bof, bof, bof};
  for (int k=0;k<64;k++){
    float wv = Wos[k][f];
    #pragma unroll
    for (int j=0;j<4;j++) acc2[j] += ps[rq*4+j][k]*wv;
  }
  #pragma unroll
  for (int j=0;j<4;j++){
    int row = row0 + rq*4 + j;
    if (row<N) out[(size_t)row*16 + f] = acc2[j];
  }
}

extern "C" void kernel_launch(void* const* d_in, const int* in_sizes, int n_in,
                              void* d_out, int out_size, void* d_ws, size_t ws_size,
                              hipStream_t stream){
  const float* x    = (const float*)d_in[0];
  const float* eatt = (const float*)d_in[1];
  const float* Win  = (const float*)d_in[2];
  const float* bin  = (const float*)d_in[3];
  const float* mW1  = (const float*)d_in[4];
  const float* mb1  = (const float*)d_in[5];
  const float* mg1  = (const float*)d_in[6];
  const float* mbe1 = (const float*)d_in[7];
  const float* mW2  = (const float*)d_in[8];
  const float* mb2  = (const float*)d_in[9];
  const float* mg2  = (const float*)d_in[10];
  const float* mbe2 = (const float*)d_in[11];
  const float* uW1  = (const float*)d_in[12];
  const float* ub1  = (const float*)d_in[13];
  const float* ug1  = (const float*)d_in[14];
  const float* ube1 = (const float*)d_in[15];
  const float* uW2  = (const float*)d_in[16];
  const float* ub2  = (const float*)d_in[17];
  const float* ug2  = (const float*)d_in[18];
  const float* ube2 = (const float*)d_in[19];
  const float* predW = (const float*)d_in[24];
  const float* predb = (const float*)d_in[25];
  const float* poutW = (const float*)d_in[26];
  const float* poutb = (const float*)d_in[27];
  const int*   ei    = (const int*)d_in[28];

  const int N = in_sizes[0] / 18;
  const int E = in_sizes[1];

  size_t nodeB = (size_t)N * 64 * sizeof(float);
  size_t halfB = (size_t)N * 64 * sizeof(u16);
  size_t t2B   = (size_t)E * 64 * sizeof(u16);
  size_t statsB = 16 * 128 * sizeof(float);
  int NB = (N + 1023)/1024;
  size_t csrB = (size_t)E*8 + (size_t)(N+1)*4 + (size_t)N*4 + (size_t)N*4 + 4096*4;

  bool planA = ws_size >= nodeB + 3*halfB + nodeB + t2B + csrB + statsB;

  char* w = (char*)d_ws;
  float* h = (float*)w; w += nodeB;
  u16* P = (u16*)w; w += halfB;
  u16* Q = (u16*)w; w += halfB;
  float* agg = (float*)w; w += nodeB;   // plan A: tn buffer; plan B: agg (aliased to tn)
  float* tn = agg;
  u16*  t2 = nullptr;
  u16*  aggh = nullptr;
  int2* seS = nullptr;
  int *rp=nullptr, *cnt=nullptr, *wrp=nullptr, *bsum=nullptr;
  float* stats;
  if (planA){
    aggh = (u16*)w;  w += halfB;
    t2   = (u16*)w;  w += t2B;
    seS  = (int2*)w; w += (size_t)E*8;
    rp   = (int*)w;  w += (size_t)(N+1)*4;
    cnt  = (int*)w;  w += (size_t)N*4;
    wrp  = (int*)w;  w += (size_t)N*4;
    bsum = (int*)w;  w += 4096*4;
    stats = (float*)w;
  } else {
    stats = (float*)w;
  }

  hipMemsetAsync(stats, 0, statsB, stream);

  int nb = (N + 63)/64;
  float invE = 1.0f/(float)E, invN = 1.0f/(float)N;

  k_in<<<nb, 256, 0, stream>>>(x, Win, bin, h, N);
  k_pq<<<nb, 256, 0, stream>>>(h, mW1, mW1 + 4096, P, Q, N);

  if (planA){
    hipMemsetAsync(cnt, 0, (size_t)N*4, stream);
    k_hist<<<(E+255)/256, 256, 0, stream>>>(ei, cnt, E);
    k_scan_a<<<NB, 256, 0, stream>>>(cnt, rp, bsum, N);
    k_scan_b<<<1, 64, 0, stream>>>(bsum, NB);
    k_scan_c<<<NB, 256, 0, stream>>>(cnt, rp, wrp, bsum, N, E);
    k_perm<<<(E+255)/256, 256, 0, stream>>>(ei, eatt, wrp, seS, E);
  }

  for (int l = 0; l < 4; ++l){
    float* s1 = stats + (l*4+0)*128;
    float* s2 = stats + (l*4+1)*128;
    float* s3 = stats + (l*4+2)*128;
    float* s4 = stats + (l*4+3)*128;
    const float* A  = mW1 + (size_t)l*8256;
    const float* c1 = A + 8192;
    if (planA){
      k_t1s<<<2048, 256, 0, stream>>>(P, Q, seS, rp, c1, mb1 + l*64, t2, s1, N);
      k_m2s<<<2048, 256, 0, stream>>>(t2, mg1 + l*64, mbe1 + l*64, s1,
                                      mW2 + (size_t)l*4096, mb2 + l*64, s2, E, invE);
      k_agg<<<2048, 256, 0, stream>>>(t2, rp, mg2 + l*64, mbe2 + l*64, s2, aggh, N, invE);
      k_up1h<<<nb, 256, 0, stream>>>(h, aggh, uW1 + (size_t)l*8192, ub1 + l*64, tn, s3, N);
    } else {
      k_s1<<<2048, 256, 0, stream>>>(P, Q, eatt, ei, c1, mb1 + l*64, s1, E);
      k_m2b<<<1024, 256, 0, stream>>>(P, Q, eatt, ei, c1, mb1 + l*64, mg1 + l*64, mbe1 + l*64,
                                      s1, mW2 + (size_t)l*4096, mb2 + l*64, s2, E, invE);
      hipMemsetAsync(agg, 0, nodeB, stream);
      k_sc_rec<<<1024, 256, 0, stream>>>(P, Q, eatt, ei, c1, mb1 + l*64, mg1 + l*64, mbe1 + l*64,
                                         s1, mW2 + (size_t)l*4096, mb2 + l*64,
                                         mg2 + l*64, mbe2 + l*64, s2, agg, E, invE);
      k_up1<<<nb, 256, 0, stream>>>(h, agg, uW1 + (size_t)l*8192, ub1 + l*64, tn, s3, N);
    }
    k_up2<<<nb, 256, 0, stream>>>(tn, ug1 + l*64, ube1 + l*64, s3, uW2 + (size_t)l*4096,
                                  ub2 + l*64, s4, N, invN);
    if (l < 3){
      const float* An = mW1 + (size_t)(l+1)*8256;
      k_res_pq<<<nb, 256, 0, stream>>>(h, tn, ug2 + l*64, ube2 + l*64, s4,
                                       An, An + 4096, P, Q, N, invN);
    } else {
      k_res_head<<<nb, 256, 0, stream>>>(h, tn, ug2 + l*64, ube2 + l*64, s4,
                                         predW, predb, poutW, poutb, (float*)d_out, N, invN);
    }
  }
}